// Round 3
// baseline (831.895 us; speedup 1.0000x reference)
//
#include <hip/hip_runtime.h>
#include <hip/hip_bf16.h>
#include <math.h>

#define Hdim 1024
#define Bsz  2
#define Slen 4096
#define Pn   256
#define NLAY 4

typedef __attribute__((ext_vector_type(8))) __bf16 bfrag;
typedef __attribute__((ext_vector_type(4))) float  f32x4;

__device__ __forceinline__ float gelu_exact(float x) {
  return 0.5f * x * (1.0f + erff(x * 0.70710678118654752f));
}
__device__ __forceinline__ short f2b(float x) {
  __hip_bfloat16 h = __float2bfloat16(x);
  return *reinterpret_cast<short*>(&h);
}
// async global->LDS DMA, 16B per lane. LDS dest is wave-uniform base + lane*16,
// so LDS layout must be linear in lane order (no padding).
__device__ __forceinline__ void gload16(const short* g, short* l) {
  __builtin_amdgcn_global_load_lds(
      (const __attribute__((address_space(1))) unsigned int*)g,
      (__attribute__((address_space(3))) unsigned int*)l, 16, 0, 0);
}
// XCD-chunk swizzle (T1, bijective when nwg % 8 == 0): round-robin dispatch ->
// each XCD gets a CONTIGUOUS chunk of tiles, so tiles sharing an A-panel hit
// the same per-XCD L2. Apply only where the natural map splits A across XCDs.
__device__ __forceinline__ void xcd_remap(int& bx, int& by) {
  int nwg = gridDim.x * gridDim.y;
  int bid = blockIdx.y * gridDim.x + blockIdx.x;
  int wg = (bid & 7) * (nwg >> 3) + (bid >> 3);
  bx = wg % gridDim.x;
  by = wg / gridDim.x;
}

// ---------------- embedding gather fused with cross-attn q LayerNorm ----------------
__global__ void embed_ln_kernel(const int* __restrict__ seq, const float* __restrict__ emb,
                                const float* __restrict__ g, const float* __restrict__ bvec,
                                float* __restrict__ x, short* __restrict__ qn) {
  int row = blockIdx.x;
  int tid = threadIdx.x;
  int tok = seq[row];
  float4 v = *(const float4*)(emb + (size_t)tok * Hdim + tid * 4);
  *(float4*)(x + (size_t)row * Hdim + tid * 4) = v;
  float s  = v.x + v.y + v.z + v.w;
  float ss = v.x * v.x + v.y * v.y + v.z * v.z + v.w * v.w;
#pragma unroll
  for (int off = 32; off; off >>= 1) { s += __shfl_xor(s, off); ss += __shfl_xor(ss, off); }
  __shared__ float rs[4], rss[4];
  int wid = tid >> 6;
  if ((tid & 63) == 0) { rs[wid] = s; rss[wid] = ss; }
  __syncthreads();
  float tot  = rs[0] + rs[1] + rs[2] + rs[3];
  float tot2 = rss[0] + rss[1] + rss[2] + rss[3];
  float mu = tot * (1.0f / Hdim);
  float var = tot2 * (1.0f / Hdim) - mu * mu;
  float rstd = rsqrtf(var + 1e-6f);
  float4 gg = *(const float4*)(g + tid * 4);
  float4 bb = *(const float4*)(bvec + tid * 4);
  short4 o;
  o.x = f2b((v.x - mu) * rstd * gg.x + bb.x);
  o.y = f2b((v.y - mu) * rstd * gg.y + bb.y);
  o.z = f2b((v.z - mu) * rstd * gg.z + bb.z);
  o.w = f2b((v.w - mu) * rstd * gg.w + bb.w);
  *(short4*)(qn + (size_t)row * Hdim + tid * 4) = o;
}

// ---------------- patch ids ----------------
__global__ void pid_kernel(const int* __restrict__ bounds, int* __restrict__ pid) {
  int i = blockIdx.x * 256 + threadIdx.x;
  int b = i >> 12;
  int s = i & (Slen - 1);
  const int* bd = bounds + b * Pn;
  int lo = 0, hi = Pn;
  while (lo < hi) { int m = (lo + hi) >> 1; if (bd[m] <= s) lo = m + 1; else hi = m; }
  pid[i] = min(lo, Pn - 1);
}

// ---------------- patch mean pooling ----------------
__global__ void pool_kernel(const float* __restrict__ x, const int* __restrict__ pid,
                            float* __restrict__ patches) {
  int bp = blockIdx.x;
  int b = bp >> 8;
  int p = bp & (Pn - 1);
  const int* pv = pid + b * Slen;
  int lo = 0, hi = Slen;
  while (lo < hi) { int m = (lo + hi) >> 1; if (pv[m] < p) lo = m + 1; else hi = m; }
  int start = lo;
  lo = 0; hi = Slen;
  while (lo < hi) { int m = (lo + hi) >> 1; if (pv[m] < p + 1) lo = m + 1; else hi = m; }
  int end = lo;
  int tid = threadIdx.x;
  float4 acc = {0.f, 0.f, 0.f, 0.f};
  for (int s = start; s < end; ++s) {
    float4 xv = *(const float4*)(x + ((size_t)(b * Slen + s)) * Hdim + tid * 4);
    acc.x += xv.x; acc.y += xv.y; acc.z += xv.z; acc.w += xv.w;
  }
  float cnt = (float)(end - start);
  float r = 1.0f / fmaxf(cnt, 1.0f);
  float4 o = {acc.x * r, acc.y * r, acc.z * r, acc.w * r};
  *(float4*)(patches + (size_t)bp * Hdim + tid * 4) = o;
}

// ---------------- LayerNorm (OBF=1 -> bf16 out) ----------------
template<int OBF>
__global__ void ln_kernel(const float* __restrict__ in, const float* __restrict__ g,
                          const float* __restrict__ bvec, void* __restrict__ outv) {
  int row = blockIdx.x;
  int tid = threadIdx.x;
  const float* xr = in + (size_t)row * Hdim;
  float4 v = *(const float4*)(xr + tid * 4);
  float s  = v.x + v.y + v.z + v.w;
  float ss = v.x * v.x + v.y * v.y + v.z * v.z + v.w * v.w;
#pragma unroll
  for (int off = 32; off; off >>= 1) { s += __shfl_xor(s, off); ss += __shfl_xor(ss, off); }
  __shared__ float rs[4], rss[4];
  int wid = tid >> 6;
  if ((tid & 63) == 0) { rs[wid] = s; rss[wid] = ss; }
  __syncthreads();
  float tot  = rs[0] + rs[1] + rs[2] + rs[3];
  float tot2 = rss[0] + rss[1] + rss[2] + rss[3];
  float mu = tot * (1.0f / Hdim);
  float var = tot2 * (1.0f / Hdim) - mu * mu;
  float rstd = rsqrtf(var + 1e-6f);
  float4 gg = *(const float4*)(g + tid * 4);
  float4 bb = *(const float4*)(bvec + tid * 4);
  float4 r;
  r.x = (v.x - mu) * rstd * gg.x + bb.x;
  r.y = (v.y - mu) * rstd * gg.y + bb.y;
  r.z = (v.z - mu) * rstd * gg.z + bb.z;
  r.w = (v.w - mu) * rstd * gg.w + bb.w;
  if (OBF) {
    short4 o; o.x = f2b(r.x); o.y = f2b(r.y); o.z = f2b(r.z); o.w = f2b(r.w);
    *(short4*)((short*)outv + (size_t)row * Hdim + tid * 4) = o;
  } else {
    *(float4*)((float*)outv + (size_t)row * Hdim + tid * 4) = r;
  }
}

// ---------------- weight convert + transpose: f32 [K,N](ldin) -> bf16 [N,K] ----------------
__global__ void wconv_kernel(const float* __restrict__ in, short* __restrict__ out,
                             int ldin, int K, size_t in_lstride, size_t out_lstride) {
  int z = blockIdx.z;
  const float* src = in + (size_t)z * in_lstride;
  short* dst = out + (size_t)z * out_lstride;
  int n0 = blockIdx.x * 32, k0 = blockIdx.y * 32;
  int tx = threadIdx.x & 31, ty = threadIdx.x >> 5;
  __shared__ float t[32][33];
#pragma unroll
  for (int i = 0; i < 4; i++)
    t[ty + 8 * i][tx] = src[(size_t)(k0 + ty + 8 * i) * ldin + n0 + tx];
  __syncthreads();
#pragma unroll
  for (int i = 0; i < 4; i++)
    dst[(size_t)(n0 + ty + 8 * i) * K + k0 + tx] = f2b(t[tx][ty + 8 * i]);
}

// ---------------- V transpose for cross attention: f32 [b,key,h*128+d] -> bf16 [bh][d][key] ----------------
__global__ void vt_kernel(const float* __restrict__ in, short* __restrict__ out) {
  int bh = blockIdx.z; int h = bh & 7; int b = bh >> 3;
  int kk0 = blockIdx.x * 32, d0 = blockIdx.y * 32;
  int tx = threadIdx.x & 31, ty = threadIdx.x >> 5;
  __shared__ float t[32][33];
  const float* src = in + (size_t)b * Pn * Hdim + h * 128;
#pragma unroll
  for (int i = 0; i < 4; i++)
    t[ty + 8 * i][tx] = src[(size_t)(kk0 + ty + 8 * i) * Hdim + d0 + tx];
  __syncthreads();
  short* dst = out + (size_t)bh * 128 * 256;
#pragma unroll
  for (int i = 0; i < 4; i++)
    dst[(size_t)(d0 + ty + 8 * i) * 256 + kk0 + tx] = f2b(t[tx][ty + 8 * i]);
}

// ---------------- V^T for global attn: bf16 qkv [b,key,3072] (v at 2048+h*64) -> [bh][d=64][key=256] ----------------
__global__ void vtg_kernel(const short* __restrict__ qkvb, short* __restrict__ out) {
  int bh = blockIdx.z; int h = bh & 15; int b = bh >> 4;
  int kk0 = blockIdx.x * 32, d0 = blockIdx.y * 32;
  int tx = threadIdx.x & 31, ty = threadIdx.x >> 5;
  __shared__ short t[32][33];
  const short* src = qkvb + (size_t)b * Pn * 3072 + 2048 + h * 64;
#pragma unroll
  for (int i = 0; i < 4; i++)
    t[ty + 8 * i][tx] = src[(size_t)(kk0 + ty + 8 * i) * 3072 + d0 + tx];
  __syncthreads();
  short* dst = out + (size_t)bh * 64 * 256;
#pragma unroll
  for (int i = 0; i < 4; i++)
    dst[(size_t)(d0 + ty + 8 * i) * 256 + kk0 + tx] = t[tx][ty + 8 * i];
}

// ---------------- bf16 MFMA GEMM 128x128, global_load_lds staging (m97 structure) ----------------
template<int EPI, int OBF, int SWZ>
__launch_bounds__(256)
__global__ void gemm_bf16(const short* __restrict__ A, const short* __restrict__ Bt,
                          const float* __restrict__ bias, const float* __restrict__ res,
                          void* __restrict__ Cv, int ldc, int K) {
  __shared__ short As[128 * 32];   // linear [row][k], unpadded (gload_lds requirement)
  __shared__ short Bs[128 * 32];
  int tid = threadIdx.x;
  int bx = blockIdx.x, by = blockIdx.y;
  if (SWZ) xcd_remap(bx, by);
  int n0 = bx * 128, m0 = by * 128;
  int lr = tid >> 2;
  int lc = (tid & 3) * 8;
  int wid = tid >> 6, lane = tid & 63;
  int wm = (wid & 1) * 64, wn = (wid >> 1) * 64;
  int quad = lane >> 4, l16 = lane & 15;
  f32x4 acc[4][4];
#pragma unroll
  for (int i = 0; i < 4; i++)
#pragma unroll
    for (int j = 0; j < 4; j++) acc[i][j] = (f32x4){0.f, 0.f, 0.f, 0.f};

  const short* ga0 = A + (size_t)(m0 + lr) * K + lc;
  const short* ga1 = A + (size_t)(m0 + lr + 64) * K + lc;
  const short* gb0 = Bt + (size_t)(n0 + lr) * K + lc;
  const short* gb1 = Bt + (size_t)(n0 + lr + 64) * K + lc;
  short* la0 = As + tid * 8;
  short* la1 = As + 2048 + tid * 8;
  short* lb0 = Bs + tid * 8;
  short* lb1 = Bs + 2048 + tid * 8;

  for (int k0 = 0; k0 < K; k0 += 32) {
    __syncthreads();                 // prev-tile fragment reads done
    gload16(ga0 + k0, la0);
    gload16(ga1 + k0, la1);
    gload16(gb0 + k0, lb0);
    gload16(gb1 + k0, lb1);
    __syncthreads();                 // compiler drains vmcnt before barrier
    bfrag af[4], bfv[4];
#pragma unroll
    for (int mi = 0; mi < 4; mi++)
      af[mi] = *reinterpret_cast<const bfrag*>(&As[(wm + mi * 16 + l16) * 32 + quad * 8]);
#pragma unroll
    for (int ni = 0; ni < 4; ni++)
      bfv[ni] = *reinterpret_cast<const bfrag*>(&Bs[(wn + ni * 16 + l16) * 32 + quad * 8]);
#pragma unroll
    for (int mi = 0; mi < 4; mi++)
#pragma unroll
      for (int ni = 0; ni < 4; ni++)
        acc[mi][ni] = __builtin_amdgcn_mfma_f32_16x16x32_bf16(af[mi], bfv[ni], acc[mi][ni], 0, 0, 0);
  }

#pragma unroll
  for (int mi = 0; mi < 4; mi++)
#pragma unroll
    for (int ni = 0; ni < 4; ni++) {
      int c = n0 + wn + ni * 16 + l16;
      float bsv = bias[c];
#pragma unroll
      for (int reg = 0; reg < 4; reg++) {
        int r = m0 + wm + mi * 16 + quad * 4 + reg;
        float v = acc[mi][ni][reg] + bsv;
        if (EPI == 1) v = gelu_exact(v);
        if (EPI == 2) v += res[(size_t)r * ldc + c];
        if (OBF) ((short*)Cv)[(size_t)r * ldc + c] = f2b(v);
        else     ((float*)Cv)[(size_t)r * ldc + c] = v;
      }
    }
}

// ---------------- bf16 MFMA GEMM 64x64, global_load_lds staging ----------------
template<int EPI, int OBF, int SWZ>
__launch_bounds__(256)
__global__ void gemm_bf16_64(const short* __restrict__ A, const short* __restrict__ Bt,
                             const float* __restrict__ bias, const float* __restrict__ res,
                             void* __restrict__ Cv, int ldc, int K) {
  __shared__ short As[64 * 32];
  __shared__ short Bs[64 * 32];
  int tid = threadIdx.x;
  int bx = blockIdx.x, by = blockIdx.y;
  if (SWZ) xcd_remap(bx, by);
  int n0 = bx * 64, m0 = by * 64;
  int lr = tid >> 2;
  int lc = (tid & 3) * 8;
  int wid = tid >> 6, lane = tid & 63;
  int wm = (wid & 1) * 32, wn = (wid >> 1) * 32;
  int quad = lane >> 4, l16 = lane & 15;
  f32x4 acc[2][2];
#pragma unroll
  for (int i = 0; i < 2; i++)
#pragma unroll
    for (int j = 0; j < 2; j++) acc[i][j] = (f32x4){0.f, 0.f, 0.f, 0.f};

  const short* ga = A + (size_t)(m0 + lr) * K + lc;
  const short* gb = Bt + (size_t)(n0 + lr) * K + lc;
  short* la = As + tid * 8;
  short* lb = Bs + tid * 8;

  for (int k0 = 0; k0 < K; k0 += 32) {
    __syncthreads();
    gload16(ga + k0, la);
    gload16(gb + k0, lb);
    __syncthreads();
    bfrag af[2], bfv[2];
#pragma unroll
    for (int mi = 0; mi < 2; mi++)
      af[mi] = *reinterpret_cast<const bfrag*>(&As[(wm + mi * 16 + l16) * 32 + quad * 8]);
#pragma unroll
    for (int ni = 0; ni < 2; ni++)
      bfv[ni] = *reinterpret_cast<const bfrag*>(&Bs[(wn + ni * 16 + l16) * 32 + quad * 8]);
#pragma unroll
    for (int mi = 0; mi < 2; mi++)
#pragma unroll
      for (int ni = 0; ni < 2; ni++)
        acc[mi][ni] = __builtin_amdgcn_mfma_f32_16x16x32_bf16(af[mi], bfv[ni], acc[mi][ni], 0, 0, 0);
  }

#pragma unroll
  for (int mi = 0; mi < 2; mi++)
#pragma unroll
    for (int ni = 0; ni < 2; ni++) {
      int c = n0 + wn + ni * 16 + l16;
      float bsv = bias[c];
#pragma unroll
      for (int reg = 0; reg < 4; reg++) {
        int r = m0 + wm + mi * 16 + quad * 4 + reg;
        float v = acc[mi][ni][reg] + bsv;
        if (EPI == 1) v = gelu_exact(v);
        if (EPI == 2) v += res[(size_t)r * ldc + c];
        if (OBF) ((short*)Cv)[(size_t)r * ldc + c] = f2b(v);
        else     ((float*)Cv)[(size_t)r * ldc + c] = v;
      }
    }
}

// ---------------- split-K GEMM for w2, global_load_lds staging ----------------
__launch_bounds__(256)
__global__ void gemm_splitk(const short* __restrict__ A, const short* __restrict__ Bt,
                            float* __restrict__ part, int K, int Ks) {
  __shared__ short As[64 * 32];
  __shared__ short Bs[64 * 32];
  int tid = threadIdx.x;
  int n0 = blockIdx.x * 64, m0 = blockIdx.y * 64, s = blockIdx.z;
  int kbase = s * Ks;
  int lr = tid >> 2;
  int lc = (tid & 3) * 8;
  int wid = tid >> 6, lane = tid & 63;
  int wm = (wid & 1) * 32, wn = (wid >> 1) * 32;
  int quad = lane >> 4, l16 = lane & 15;
  f32x4 acc[2][2];
#pragma unroll
  for (int i = 0; i < 2; i++)
#pragma unroll
    for (int j = 0; j < 2; j++) acc[i][j] = (f32x4){0.f, 0.f, 0.f, 0.f};

  const short* ga = A + (size_t)(m0 + lr) * K + lc;
  const short* gb = Bt + (size_t)(n0 + lr) * K + lc;
  short* la = As + tid * 8;
  short* lb = Bs + tid * 8;

  for (int k0 = kbase; k0 < kbase + Ks; k0 += 32) {
    __syncthreads();
    gload16(ga + k0, la);
    gload16(gb + k0, lb);
    __syncthreads();
    bfrag af[2], bfv[2];
#pragma unroll
    for (int mi = 0; mi < 2; mi++)
      af[mi] = *reinterpret_cast<const bfrag*>(&As[(wm + mi * 16 + l16) * 32 + quad * 8]);
#pragma unroll
    for (int ni = 0; ni < 2; ni++)
      bfv[ni] = *reinterpret_cast<const bfrag*>(&Bs[(wn + ni * 16 + l16) * 32 + quad * 8]);
#pragma unroll
    for (int mi = 0; mi < 2; mi++)
#pragma unroll
      for (int ni = 0; ni < 2; ni++)
        acc[mi][ni] = __builtin_amdgcn_mfma_f32_16x16x32_bf16(af[mi], bfv[ni], acc[mi][ni], 0, 0, 0);
  }

#pragma unroll
  for (int mi = 0; mi < 2; mi++)
#pragma unroll
    for (int ni = 0; ni < 2; ni++) {
      int c = n0 + wn + ni * 16 + l16;
#pragma unroll
      for (int reg = 0; reg < 4; reg++) {
        int r = m0 + wm + mi * 16 + quad * 4 + reg;
        part[(size_t)s * 524288 + (size_t)r * 1024 + c] = acc[mi][ni][reg];
      }
    }
}

// reduce 4 partials + bias + residual -> patches (f32)
__global__ void w2red_kernel(const float* __restrict__ part, const float* __restrict__ bias,
                             float* __restrict__ patches) {
  int i = (blockIdx.x * 256 + threadIdx.x) * 4;  // over 512*1024 elems
  float4 v = *(const float4*)(part + i);
#pragma unroll
  for (int s = 1; s < 4; s++) {
    float4 p = *(const float4*)(part + (size_t)s * 524288 + i);
    v.x += p.x; v.y += p.y; v.z += p.z; v.w += p.w;
  }
  int c = i & 1023;
  float4 bv = *(const float4*)(bias + c);
  float4 rv = *(const float4*)(patches + i);
  v.x += bv.x + rv.x; v.y += bv.y + rv.y; v.z += bv.z + rv.z; v.w += bv.w + rv.w;
  *(float4*)(patches + i) = v;
}

// ---------------- global self-attn MFMA: nh=16, dh=64, P=256, causal ----------------
__launch_bounds__(256)
__global__ void attn_global3(const short* __restrict__ qkvb, const short* __restrict__ vtg,
                             short* __restrict__ outp) {
  int qt = blockIdx.x;
  int bh = blockIdx.y; int h = bh & 15, b = bh >> 4;
  int tid = threadIdx.x;
  int wid = tid >> 6, lane = tid & 63;
  int quad = lane >> 4, l16 = lane & 15;
  int q0 = qt * 64 + wid * 16;
  __shared__ short KV[64 * 72];
  __shared__ short Pl[4][16][264];
  const short* qrow = qkvb + ((size_t)(b * Pn + q0 + l16)) * 3072 + h * 64 + quad * 8;
  bfrag qf[2];
#pragma unroll
  for (int kd = 0; kd < 2; kd++) qf[kd] = *(const bfrag*)(qrow + kd * 32);
  f32x4 sacc[16];
#pragma unroll
  for (int n = 0; n < 16; n++) sacc[n] = (f32x4){0.f, 0.f, 0.f, 0.f};
  int cr = tid >> 2, cc = (tid & 3) * 16;
#pragma unroll
  for (int kc = 0; kc < 4; kc++) {
    if (kc <= qt) {
      const short* ksrc = qkvb + ((size_t)(b * Pn + kc * 64 + cr)) * 3072 + 1024 + h * 64 + cc;
      int4 v0 = *(const int4*)(ksrc);
      int4 v1 = *(const int4*)(ksrc + 8);
      __syncthreads();
      *(int4*)&KV[cr * 72 + cc] = v0;
      *(int4*)&KV[cr * 72 + cc + 8] = v1;
      __syncthreads();
#pragma unroll
      for (int n = 0; n < 4; n++)
#pragma unroll
        for (int kd = 0; kd < 2; kd++) {
          bfrag kf = *(const bfrag*)&KV[(n * 16 + l16) * 72 + kd * 32 + quad * 8];
          sacc[kc * 4 + n] = __builtin_amdgcn_mfma_f32_16x16x32_bf16(qf[kd], kf, sacc[kc * 4 + n], 0, 0, 0);
        }
    }
  }
  int nfr = (qt + 1) * 4;
  const float scale = 0.125f;
  float mx[4] = {-1e30f, -1e30f, -1e30f, -1e30f};
#pragma unroll
  for (int n = 0; n < 16; n++) {
    if (n < nfr) {
      int col = n * 16 + l16;
#pragma unroll
      for (int r = 0; r < 4; r++)
        if (col <= q0 + quad * 4 + r) mx[r] = fmaxf(mx[r], sacc[n][r]);
    }
  }
#pragma unroll
  for (int off = 1; off < 16; off <<= 1)
#pragma unroll
    for (int r = 0; r < 4; r++) mx[r] = fmaxf(mx[r], __shfl_xor(mx[r], off));
  float ls[4] = {0.f, 0.f, 0.f, 0.f};
#pragma unroll
  for (int n = 0; n < 16; n++) {
    if (n < nfr) {
      int col = n * 16 + l16;
#pragma unroll
      for (int r = 0; r < 4; r++) {
        float p = (col <= q0 + quad * 4 + r) ? __expf((sacc[n][r] - mx[r]) * scale) : 0.f;
        Pl[wid][quad * 4 + r][col] = f2b(p);
        ls[r] += p;
      }
    }
  }
#pragma unroll
  for (int off = 1; off < 16; off <<= 1)
#pragma unroll
    for (int r = 0; r < 4; r++) ls[r] += __shfl_xor(ls[r], off);
  float rl[4];
#pragma unroll
  for (int r = 0; r < 4; r++) rl[r] = 1.0f / ls[r];

  f32x4 oacc[4];
#pragma unroll
  for (int n = 0; n < 4; n++) oacc[n] = (f32x4){0.f, 0.f, 0.f, 0.f};
#pragma unroll
  for (int kc = 0; kc < 4; kc++) {
    if (kc <= qt) {
      const short* vsrc = vtg + (size_t)bh * 64 * 256 + cr * 256 + kc * 64 + cc;
      int4 v0 = *(const int4*)(vsrc);
      int4 v1 = *(const int4*)(vsrc + 8);
      __syncthreads();
      *(int4*)&KV[cr * 72 + cc] = v0;
      *(int4*)&KV[cr * 72 + cc + 8] = v1;
      __syncthreads();
#pragma unroll
      for (int kk = 0; kk < 2; kk++) {
        bfrag pa = *(const bfrag*)&Pl[wid][l16][kc * 64 + kk * 32 + quad * 8];
#pragma unroll
        for (int n = 0; n < 4; n++) {
          bfrag vf = *(const bfrag*)&KV[(n * 16 + l16) * 72 + kk * 32 + quad * 8];
          oacc[n] = __builtin_amdgcn_mfma_f32_16x16x32_bf16(pa, vf, oacc[n], 0, 0, 0);
        }
      }
    }
  }
#pragma unroll
  for (int n = 0; n < 4; n++)
#pragma unroll
    for (int r = 0; r < 4; r++)
      outp[(size_t)(b * Pn + q0 + quad * 4 + r) * Hdim + h * 64 + n * 16 + l16] = f2b(oacc[n][r] * rl[r]);
}

// ---------------- cross-attn MFMA v4: LDS-staged K/V chunks. nh=8, dh=128, Lq=4096, Lk=256 ----------------
__launch_bounds__(256)
__global__ void attn_cross4(const short* __restrict__ q, const short* __restrict__ k,
                            const short* __restrict__ vt, short* __restrict__ outp) {
  int bh = blockIdx.y; int h = bh & 7, b = bh >> 3;
  int tid = threadIdx.x;
  int wid = tid >> 6, lane = tid & 63;
  int quad = lane >> 4, l16 = lane & 15;
  int q0 = blockIdx.x * 64 + wid * 16;
  __shared__ short KV[9216];
  __shared__ short Pl[4][16][264];
  const short* qrow = q + ((size_t)(b * Slen + q0 + l16)) * Hdim + h * 128 + quad * 8;
  bfrag qf[4];
#pragma unroll
  for (int kd = 0; kd < 4; kd++) qf[kd] = *(const bfrag*)(qrow + kd * 32);
  f32x4 sacc[16];
#pragma unroll
  for (int n = 0; n < 16; n++) sacc[n] = (f32x4){0.f, 0.f, 0.f, 0.f};

  int cr4 = tid >> 2, cc4 = (tid & 3) * 32;
#pragma unroll
  for (int kc = 0; kc < 4; kc++) {
    const short* ksrc = k + ((size_t)(b * Pn + kc * 64 + cr4)) * Hdim + h * 128 + cc4;
    int4 v0 = *(const int4*)(ksrc);
    int4 v1 = *(const int4*)(ksrc + 8);
    int4 v2 = *(const int4*)(ksrc + 16);
    int4 v3 = *(const int4*)(ksrc + 24);
    __syncthreads();
    *(int4*)&KV[cr4 * 136 + cc4]      = v0;
    *(int4*)&KV[cr4 * 136 + cc4 + 8]  = v1;
    *(int4*)&KV[cr4 * 136 + cc4 + 16] = v2;
    *(int4*)&KV[cr4 * 136 + cc4 + 24] = v3;
    __syncthreads();
#pragma unroll
    for (int n = 0; n < 4; n++)
#pragma unroll
      for (int kd = 0; kd < 4; kd++) {
        bfrag kf = *(const bfrag*)&KV[(n * 16 + l16) * 136 + kd * 32 + quad * 8];
        sacc[kc * 4 + n] = __builtin_amdgcn_mfma_f32_16x16x32_bf16(qf[kd], kf, sacc[kc * 4 + n], 0, 0, 0);
      }
  }

  const float scale = 0.088388347648318447f;
  float mx[4] = {-1e30f, -1e30f, -1e30f, -1e30f};
#pragma unroll
  for (int n = 0; n < 16; n++)
#pragma unroll
    for (int r = 0; r < 4; r++) mx[r] = fmaxf(mx[r], sacc[n][r]);
#pragma unroll
  for (int off = 1; off < 16; off <<= 1)
#pragma unroll
    for (int r = 0; r < 4; r++) mx[r] = fmaxf(mx[r], __shfl_xor(mx[r], off));
  float ls[4] = {0.f, 0.f, 0.f, 0.f};
#pragma unroll
  for (int n = 0; n < 16; n++)
#pragma unroll
    for (int r = 0; r < 4; r++) {
      float p = __expf((sacc[n][r] - mx[r]) * scale);
      Pl[wid][quad * 4 + r][n * 16 + l16] = f2b(p);
      ls[r] += p;
    }
#pragma unroll
  for (int off = 1; off < 16; off <<= 1)
#pragma unroll
    for (int r = 0; r < 4; r++) ls[r] += __shfl_xor(ls[r], off);
  float rl[4];
#pragma unroll
  for (int r = 0; r < 4; r++) rl[r] = 1.0f / ls[r];

  f32x4 oacc[8];
#pragma unroll
  for (int n = 0; n < 8; n++) oacc[n] = (f32x4){0.f, 0.f, 0.f, 0.f};
  int cr2 = tid >> 1, cc2 = (tid & 1) * 32;
#pragma unroll
  for (int kc = 0; kc < 4; kc++) {
    const short* vsrc = vt + (size_t)bh * 32768 + cr2 * 256 + kc * 64 + cc2;
    int4 v0 = *(const int4*)(vsrc);
    int4 v1 = *(const int4*)(vsrc + 8);
    int4 v2 = *(const int4*)(vsrc + 16);
    int4 v3 = *(const int4*)(vsrc + 24);
    __syncthreads();
    *(int4*)&KV[cr2 * 72 + cc2]      = v0;
    *(int4*)&KV[cr2 * 72 + cc2 + 8]  = v1;
    *(int4*)&KV[cr2 * 72 + cc2 + 16] = v2;
    *(int4*)&KV[cr2 * 72 + cc2 + 24] = v3;
    __syncthreads();
#pragma unroll
    for (int kk = 0; kk < 2; kk++) {
      bfrag pa = *(const bfrag*)&Pl[wid][l16][kc * 64 + kk * 32 + quad * 8];
#pragma unroll
      for (int n = 0; n < 8; n++) {
        bfrag vf = *(const bfrag*)&KV[(n * 16 + l16) * 72 + kk * 32 + quad * 8];
        oacc[n] = __builtin_amdgcn_mfma_f32_16x16x32_bf16(pa, vf, oacc[n], 0, 0, 0);
      }
    }
  }
#pragma unroll
  for (int n = 0; n < 8; n++)
#pragma unroll
    for (int r = 0; r < 4; r++)
      outp[(size_t)(b * Slen + q0 + quad * 4 + r) * Hdim + h * 128 + n * 16 + l16] = f2b(oacc[n][r] * rl[r]);
}

extern "C" void kernel_launch(void* const* d_in, const int* in_sizes, int n_in,
                              void* d_out, int out_size, void* d_ws, size_t ws_size,
                              hipStream_t stream) {
  const int*   byte_seq = (const int*)d_in[0];
  const int*   pbound   = (const int*)d_in[1];
  const float* emb      = (const float*)d_in[2];
  const float* g_ln1_g  = (const float*)d_in[3];
  const float* g_ln1_b  = (const float*)d_in[4];
  const float* g_wqkv   = (const float*)d_in[5];
  const float* g_bqkv   = (const float*)d_in[6];
  const float* g_wo     = (const float*)d_in[7];
  const float* g_bo     = (const float*)d_in[8];
  const float* g_ln2_g  = (const float*)d_in[9];
  const float* g_ln2_b  = (const float*)d_in[10];
  const float* g_w1     = (const float*)d_in[11];
  const float* g_b1     = (const float*)d_in[12];
  const float* g_w2     = (const float*)d_in[13];
  const float* g_b2     = (const float*)d_in[14];
  const float* fn_g     = (const float*)d_in[15];
  const float* fn_b     = (const float*)d_in[16];
  const float* ca_ln_g  = (const float*)d_in[17];
  const float* ca_ln_b  = (const float*)d_in[18];
  const float* ca_wqkv  = (const float*)d_in[19];
  const float* ca_bqkv  = (const float*)d_in[20];
  const float* ca_wo    = (const float*)d_in[21];
  const float* ca_bo    = (const float*)d_in[22];
  const float* head_w   = (const float*)d_in[23];
  const float* head_b   = (const float*)d_in[24];
  float* out = (float*)d_out;

  // ---- workspace layout ----
  float* x       = (float*)d_ws;                 // 8388608 f32
  float* patches = x + 8388608;                  // 524288
  float* vbuf    = patches + 524288;             // 524288
  float* w2part  = vbuf + 524288;                // 2097152 (4 x 512x1024 partials)
  int*   pid     = (int*)(w2part + 2097152);     // 8192 ints
  short* nbuf    = (short*)(pid + 8192);         // 524288 bf16
  short* attn_o  = nbuf + 524288;                // 524288
  short* mid     = attn_o + 524288;              // 2097152
  short* qn      = mid + 2097152;                // 8388608 (LN(x); reused as caout)
  short* qb      = qn + 8388608;                 // 8388608
  short* xb      = qb + 8388608;                 // 8388608
  short* kb      = xb + 8388608;                 // 524288 (cross K bf16)
  short* vt      = kb + 524288;                  // 524288 (cross V^T bf16)
  short* qkvb    = vt + 524288;                  // 1572864 (layer qkv bf16)
  short* vtg     = qkvb + 1572864;               // 524288 (global V^T bf16)
  short* wqkv_t  = vtg + 524288;                 // 12582912
  short* wo_t    = wqkv_t + 12582912;            // 4194304
  short* w1_t    = wo_t + 4194304;               // 16777216
  short* w2_t    = w1_t + 16777216;              // 16777216
  short* caq_t   = w2_t + 16777216;              // 1048576
  short* cak_t   = caq_t + 1048576;              // 1048576
  short* cav_t   = cak_t + 1048576;              // 1048576
  short* cawo_t  = cav_t + 1048576;              // 1048576
  short* head_t  = cawo_t + 1048576;             // 262144
  short* caout   = qn;                           // alias (qn dead after q-proj)

  // 1. byte embeddings (+fused cross-attn q LayerNorm), patch ids, pooling
  embed_ln_kernel<<<Bsz * Slen, 256, 0, stream>>>(byte_seq, emb, ca_ln_g, ca_ln_b, x, qn);
  pid_kernel<<<(Bsz * Slen) / 256, 256, 0, stream>>>(pbound, pid);
  pool_kernel<<<Bsz * Pn, 256, 0, stream>>>(x, pid, patches);

  // 2. weight convert + transpose to bf16 [N,K]
  wconv_kernel<<<dim3(96, 32, 4), 256, 0, stream>>>(g_wqkv, wqkv_t, 3072, 1024, 3145728, 3145728);
  wconv_kernel<<<dim3(32, 32, 4), 256, 0, stream>>>(g_wo, wo_t, 1024, 1024, 1048576, 1048576);
  wconv_kernel<<<dim3(128, 32, 4), 256, 0, stream>>>(g_w1, w1_t, 4096, 1024, 4194304, 4194304);
  wconv_kernel<<<dim3(32, 128, 4), 256, 0, stream>>>(g_w2, w2_t, 1024, 4096, 4194304, 4194304);
  wconv_kernel<<<dim3(32, 32, 3), 256, 0, stream>>>(ca_wqkv, caq_t, 3072, 1024, 1024, 1048576);
  wconv_kernel<<<dim3(32, 32, 1), 256, 0, stream>>>(ca_wo, cawo_t, 1024, 1024, 0, 0);
  wconv_kernel<<<dim3(8, 32, 1), 256, 0, stream>>>(head_w, head_t, 256, 1024, 0, 0);

  // 3. global transformer layers (natural blockIdx: XCD = bx%8 keeps B-panels
  //    XCD-local for these shapes; do NOT swizzle)
  for (int l = 0; l < NLAY; ++l) {
    ln_kernel<1><<<Bsz * Pn, 256, 0, stream>>>(patches, g_ln1_g + l * Hdim, g_ln1_b + l * Hdim, nbuf);
    gemm_bf16_64<0, 1, 0><<<dim3(48, 8), 256, 0, stream>>>(
        nbuf, wqkv_t + (size_t)l * 3145728, g_bqkv + l * 3072, nullptr, qkvb, 3072, 1024);
    vtg_kernel<<<dim3(8, 2, 32), 256, 0, stream>>>(qkvb, vtg);
    attn_global3<<<dim3(4, 32), 256, 0, stream>>>(qkvb, vtg, attn_o);
    gemm_bf16_64<2, 0, 0><<<dim3(16, 8), 256, 0, stream>>>(
        attn_o, wo_t + (size_t)l * 1048576, g_bo + l * Hdim, patches, patches, 1024, 1024);
    ln_kernel<1><<<Bsz * Pn, 256, 0, stream>>>(patches, g_ln2_g + l * Hdim, g_ln2_b + l * Hdim, nbuf);
    gemm_bf16_64<1, 1, 0><<<dim3(64, 8), 256, 0, stream>>>(
        nbuf, w1_t + (size_t)l * 4194304, g_b1 + l * 4096, nullptr, mid, 4096, 1024);
    gemm_splitk<<<dim3(16, 8, 4), 256, 0, stream>>>(
        mid, w2_t + (size_t)l * 4194304, w2part, 4096, 1024);
    w2red_kernel<<<512, 256, 0, stream>>>(w2part, g_b2 + l * Hdim, patches);
  }

  // 4. final norm (f32, in-place), then cross-attn LN of patches -> bf16
  ln_kernel<0><<<Bsz * Pn, 256, 0, stream>>>(patches, fn_g, fn_b, patches);
  ln_kernel<1><<<Bsz * Pn, 256, 0, stream>>>(patches, ca_ln_g, ca_ln_b, nbuf);

  // 5. k (bf16 out), v (f32 out -> transposed bf16)
  gemm_bf16_64<0, 1, 0><<<dim3(16, 8), 256, 0, stream>>>(
      nbuf, cak_t, ca_bqkv + 1024, nullptr, kb, 1024, 1024);
  gemm_bf16_64<0, 0, 0><<<dim3(16, 8), 256, 0, stream>>>(
      nbuf, cav_t, ca_bqkv + 2048, nullptr, vbuf, 1024, 1024);
  vt_kernel<<<dim3(8, 4, 16), 256, 0, stream>>>(vbuf, vt);

  // 6. q projection from fused LN(x) -> bf16 (M=8192: swizzle for A-panel L2 reuse)
  gemm_bf16<0, 1, 1><<<dim3(8, 64), 256, 0, stream>>>(
      qn, caq_t, ca_bqkv, nullptr, qb, 1024, 1024);

  // 7. MFMA cross attention (qn dead; caout aliases it)
  attn_cross4<<<dim3(64, 16), 256, 0, stream>>>(qb, kb, vt, caout);

  // 8. output projection + residual -> xb (bf16, feeds head)
  gemm_bf16<2, 1, 1><<<dim3(8, 64), 256, 0, stream>>>(
      caout, cawo_t, ca_bo, x, xb, 1024, 1024);

  // 9. head (M=8192: swizzle)
  gemm_bf16_64<0, 0, 1><<<dim3(4, 128), 256, 0, stream>>>(
      xb, head_t, head_b, nullptr, out, 256, 1024);
}

// Round 4
// 771.473 us; speedup vs baseline: 1.0783x; 1.0783x over previous
//
#include <hip/hip_runtime.h>
#include <hip/hip_bf16.h>
#include <math.h>

#define Hdim 1024
#define Bsz  2
#define Slen 4096
#define Pn   256
#define NLAY 4

typedef __attribute__((ext_vector_type(8))) __bf16 bfrag;
typedef __attribute__((ext_vector_type(4))) float  f32x4;

__device__ __forceinline__ float gelu_exact(float x) {
  return 0.5f * x * (1.0f + erff(x * 0.70710678118654752f));
}
__device__ __forceinline__ short f2b(float x) {
  __hip_bfloat16 h = __float2bfloat16(x);
  return *reinterpret_cast<short*>(&h);
}
// async global->LDS DMA, 16B per lane. LDS dest is wave-uniform base + lane*16,
// so LDS layout must be linear in lane order (no padding).
__device__ __forceinline__ void gload16(const short* g, short* l) {
  __builtin_amdgcn_global_load_lds(
      (const __attribute__((address_space(1))) unsigned int*)g,
      (__attribute__((address_space(3))) unsigned int*)l, 16, 0, 0);
}
// XCD-chunk swizzle (T1, bijective when nwg % 8 == 0).
__device__ __forceinline__ void xcd_remap(int& bx, int& by) {
  int nwg = gridDim.x * gridDim.y;
  int bid = blockIdx.y * gridDim.x + blockIdx.x;
  int wg = (bid & 7) * (nwg >> 3) + (bid >> 3);
  bx = wg % gridDim.x;
  by = wg / gridDim.x;
}

// ---------------- embedding gather fused with cross-attn q LayerNorm ----------------
__global__ void embed_ln_kernel(const int* __restrict__ seq, const float* __restrict__ emb,
                                const float* __restrict__ g, const float* __restrict__ bvec,
                                float* __restrict__ x, short* __restrict__ qn) {
  int row = blockIdx.x;
  int tid = threadIdx.x;
  int tok = seq[row];
  float4 v = *(const float4*)(emb + (size_t)tok * Hdim + tid * 4);
  *(float4*)(x + (size_t)row * Hdim + tid * 4) = v;
  float s  = v.x + v.y + v.z + v.w;
  float ss = v.x * v.x + v.y * v.y + v.z * v.z + v.w * v.w;
#pragma unroll
  for (int off = 32; off; off >>= 1) { s += __shfl_xor(s, off); ss += __shfl_xor(ss, off); }
  __shared__ float rs[4], rss[4];
  int wid = tid >> 6;
  if ((tid & 63) == 0) { rs[wid] = s; rss[wid] = ss; }
  __syncthreads();
  float tot  = rs[0] + rs[1] + rs[2] + rs[3];
  float tot2 = rss[0] + rss[1] + rss[2] + rss[3];
  float mu = tot * (1.0f / Hdim);
  float var = tot2 * (1.0f / Hdim) - mu * mu;
  float rstd = rsqrtf(var + 1e-6f);
  float4 gg = *(const float4*)(g + tid * 4);
  float4 bb = *(const float4*)(bvec + tid * 4);
  short4 o;
  o.x = f2b((v.x - mu) * rstd * gg.x + bb.x);
  o.y = f2b((v.y - mu) * rstd * gg.y + bb.y);
  o.z = f2b((v.z - mu) * rstd * gg.z + bb.z);
  o.w = f2b((v.w - mu) * rstd * gg.w + bb.w);
  *(short4*)(qn + (size_t)row * Hdim + tid * 4) = o;
}

// ---------------- patch ids ----------------
__global__ void pid_kernel(const int* __restrict__ bounds, int* __restrict__ pid) {
  int i = blockIdx.x * 256 + threadIdx.x;
  int b = i >> 12;
  int s = i & (Slen - 1);
  const int* bd = bounds + b * Pn;
  int lo = 0, hi = Pn;
  while (lo < hi) { int m = (lo + hi) >> 1; if (bd[m] <= s) lo = m + 1; else hi = m; }
  pid[i] = min(lo, Pn - 1);
}

// ---------------- patch mean pooling ----------------
__global__ void pool_kernel(const float* __restrict__ x, const int* __restrict__ pid,
                            float* __restrict__ patches) {
  int bp = blockIdx.x;
  int b = bp >> 8;
  int p = bp & (Pn - 1);
  const int* pv = pid + b * Slen;
  int lo = 0, hi = Slen;
  while (lo < hi) { int m = (lo + hi) >> 1; if (pv[m] < p) lo = m + 1; else hi = m; }
  int start = lo;
  lo = 0; hi = Slen;
  while (lo < hi) { int m = (lo + hi) >> 1; if (pv[m] < p + 1) lo = m + 1; else hi = m; }
  int end = lo;
  int tid = threadIdx.x;
  float4 acc = {0.f, 0.f, 0.f, 0.f};
  for (int s = start; s < end; ++s) {
    float4 xv = *(const float4*)(x + ((size_t)(b * Slen + s)) * Hdim + tid * 4);
    acc.x += xv.x; acc.y += xv.y; acc.z += xv.z; acc.w += xv.w;
  }
  float cnt = (float)(end - start);
  float r = 1.0f / fmaxf(cnt, 1.0f);
  float4 o = {acc.x * r, acc.y * r, acc.z * r, acc.w * r};
  *(float4*)(patches + (size_t)bp * Hdim + tid * 4) = o;
}

// ---------------- LayerNorm (OBF=1 -> bf16 out) ----------------
template<int OBF>
__global__ void ln_kernel(const float* __restrict__ in, const float* __restrict__ g,
                          const float* __restrict__ bvec, void* __restrict__ outv) {
  int row = blockIdx.x;
  int tid = threadIdx.x;
  const float* xr = in + (size_t)row * Hdim;
  float4 v = *(const float4*)(xr + tid * 4);
  float s  = v.x + v.y + v.z + v.w;
  float ss = v.x * v.x + v.y * v.y + v.z * v.z + v.w * v.w;
#pragma unroll
  for (int off = 32; off; off >>= 1) { s += __shfl_xor(s, off); ss += __shfl_xor(ss, off); }
  __shared__ float rs[4], rss[4];
  int wid = tid >> 6;
  if ((tid & 63) == 0) { rs[wid] = s; rss[wid] = ss; }
  __syncthreads();
  float tot  = rs[0] + rs[1] + rs[2] + rs[3];
  float tot2 = rss[0] + rss[1] + rss[2] + rss[3];
  float mu = tot * (1.0f / Hdim);
  float var = tot2 * (1.0f / Hdim) - mu * mu;
  float rstd = rsqrtf(var + 1e-6f);
  float4 gg = *(const float4*)(g + tid * 4);
  float4 bb = *(const float4*)(bvec + tid * 4);
  float4 r;
  r.x = (v.x - mu) * rstd * gg.x + bb.x;
  r.y = (v.y - mu) * rstd * gg.y + bb.y;
  r.z = (v.z - mu) * rstd * gg.z + bb.z;
  r.w = (v.w - mu) * rstd * gg.w + bb.w;
  if (OBF) {
    short4 o; o.x = f2b(r.x); o.y = f2b(r.y); o.z = f2b(r.z); o.w = f2b(r.w);
    *(short4*)((short*)outv + (size_t)row * Hdim + tid * 4) = o;
  } else {
    *(float4*)((float*)outv + (size_t)row * Hdim + tid * 4) = r;
  }
}

// ---------------- weight convert + transpose: f32 [K,N](ldin) -> bf16 [N,K] ----------------
__global__ void wconv_kernel(const float* __restrict__ in, short* __restrict__ out,
                             int ldin, int K, size_t in_lstride, size_t out_lstride) {
  int z = blockIdx.z;
  const float* src = in + (size_t)z * in_lstride;
  short* dst = out + (size_t)z * out_lstride;
  int n0 = blockIdx.x * 32, k0 = blockIdx.y * 32;
  int tx = threadIdx.x & 31, ty = threadIdx.x >> 5;
  __shared__ float t[32][33];
#pragma unroll
  for (int i = 0; i < 4; i++)
    t[ty + 8 * i][tx] = src[(size_t)(k0 + ty + 8 * i) * ldin + n0 + tx];
  __syncthreads();
#pragma unroll
  for (int i = 0; i < 4; i++)
    dst[(size_t)(n0 + ty + 8 * i) * K + k0 + tx] = f2b(t[tx][ty + 8 * i]);
}

// ---------------- V transpose for cross attention: f32 [b,key,h*128+d] -> bf16 [bh][d][key] ----------------
__global__ void vt_kernel(const float* __restrict__ in, short* __restrict__ out) {
  int bh = blockIdx.z; int h = bh & 7; int b = bh >> 3;
  int kk0 = blockIdx.x * 32, d0 = blockIdx.y * 32;
  int tx = threadIdx.x & 31, ty = threadIdx.x >> 5;
  __shared__ float t[32][33];
  const float* src = in + (size_t)b * Pn * Hdim + h * 128;
#pragma unroll
  for (int i = 0; i < 4; i++)
    t[ty + 8 * i][tx] = src[(size_t)(kk0 + ty + 8 * i) * Hdim + d0 + tx];
  __syncthreads();
  short* dst = out + (size_t)bh * 128 * 256;
#pragma unroll
  for (int i = 0; i < 4; i++)
    dst[(size_t)(d0 + ty + 8 * i) * 256 + kk0 + tx] = f2b(t[tx][ty + 8 * i]);
}

// ---------------- V^T for global attn: bf16 qkv [b,key,3072] (v at 2048+h*64) -> [bh][d=64][key=256] ----------------
__global__ void vtg_kernel(const short* __restrict__ qkvb, short* __restrict__ out) {
  int bh = blockIdx.z; int h = bh & 15; int b = bh >> 4;
  int kk0 = blockIdx.x * 32, d0 = blockIdx.y * 32;
  int tx = threadIdx.x & 31, ty = threadIdx.x >> 5;
  __shared__ short t[32][33];
  const short* src = qkvb + (size_t)b * Pn * 3072 + 2048 + h * 64;
#pragma unroll
  for (int i = 0; i < 4; i++)
    t[ty + 8 * i][tx] = src[(size_t)(kk0 + ty + 8 * i) * 3072 + d0 + tx];
  __syncthreads();
  short* dst = out + (size_t)bh * 64 * 256;
#pragma unroll
  for (int i = 0; i < 4; i++)
    dst[(size_t)(d0 + ty + 8 * i) * 256 + kk0 + tx] = t[tx][ty + 8 * i];
}

// ---------------- bf16 MFMA GEMM 128x128, BK=64, dbuf LDS + 2-phase prefetch ----------------
// T3 minimum-2-phase: STAGE(next) -> ds_read+MFMA(cur) -> vmcnt(0) -> raw barrier.
// LDS rows are 128B: XOR-swizzle 16B chunk index with (row&7); gload_lds dest stays
// linear, global SOURCE chunk is pre-swizzled, ds_read applies same XOR (rule #21).
template<int EPI, int OBF, int SWZ>
__launch_bounds__(256)
__global__ void gemm_bf16(const short* __restrict__ A, const short* __restrict__ Bt,
                          const float* __restrict__ bias, const float* __restrict__ res,
                          void* __restrict__ Cv, int ldc, int K) {
  __shared__ short As[2][128 * 64];   // 32 KB
  __shared__ short Bs[2][128 * 64];   // 32 KB
  int tid = threadIdx.x;
  int bx = blockIdx.x, by = blockIdx.y;
  if (SWZ) xcd_remap(bx, by);
  int n0 = bx * 128, m0 = by * 128;
  int lr = tid >> 3;                       // 0..31 (staging row within round)
  int lc = (((tid & 7) ^ (lr & 7)) * 8);   // pre-swizzled source chunk
  int wid = tid >> 6, lane = tid & 63;
  int wm = (wid & 1) * 64, wn = (wid >> 1) * 64;
  int quad = lane >> 4, l16 = lane & 15;
  f32x4 acc[4][4];
#pragma unroll
  for (int i = 0; i < 4; i++)
#pragma unroll
    for (int j = 0; j < 4; j++) acc[i][j] = (f32x4){0.f, 0.f, 0.f, 0.f};

  const short* ga = A + (size_t)(m0 + lr) * K + lc;
  const short* gb = Bt + (size_t)(n0 + lr) * K + lc;
  short* la = &As[0][tid * 8];     // linear DMA dest; buffer stride 8192 shorts
  short* lb = &Bs[0][tid * 8];

  // prologue: stage tile 0 into buf 0
#pragma unroll
  for (int r = 0; r < 4; r++) {
    gload16(ga + (size_t)(r * 32) * K, la + r * 2048);
    gload16(gb + (size_t)(r * 32) * K, lb + r * 2048);
  }
  asm volatile("s_waitcnt vmcnt(0)" ::: "memory");
  __builtin_amdgcn_s_barrier();

  int NT = K >> 6;
  for (int t = 0; t < NT; ++t) {
    int cur = t & 1;
    if (t + 1 < NT) {                // issue next-tile loads (hidden under MFMA)
      int nb = (cur ^ 1) * 8192;
      int k1 = (t + 1) << 6;
#pragma unroll
      for (int r = 0; r < 4; r++) {
        gload16(ga + (size_t)(r * 32) * K + k1, la + nb + r * 2048);
        gload16(gb + (size_t)(r * 32) * K + k1, lb + nb + r * 2048);
      }
    }
#pragma unroll
    for (int kk = 0; kk < 2; kk++) {
      bfrag af[4], bfv[4];
#pragma unroll
      for (int mi = 0; mi < 4; mi++) {
        int row = wm + mi * 16 + l16;
        af[mi] = *reinterpret_cast<const bfrag*>(
            &As[cur][row * 64 + (((kk * 4 + quad) ^ (row & 7)) * 8)]);
      }
#pragma unroll
      for (int ni = 0; ni < 4; ni++) {
        int row = wn + ni * 16 + l16;
        bfv[ni] = *reinterpret_cast<const bfrag*>(
            &Bs[cur][row * 64 + (((kk * 4 + quad) ^ (row & 7)) * 8)]);
      }
#pragma unroll
      for (int mi = 0; mi < 4; mi++)
#pragma unroll
        for (int ni = 0; ni < 4; ni++)
          acc[mi][ni] = __builtin_amdgcn_mfma_f32_16x16x32_bf16(af[mi], bfv[ni], acc[mi][ni], 0, 0, 0);
    }
    asm volatile("s_waitcnt vmcnt(0)" ::: "memory");   // next tile landed
    __builtin_amdgcn_s_barrier();
  }

#pragma unroll
  for (int mi = 0; mi < 4; mi++)
#pragma unroll
    for (int ni = 0; ni < 4; ni++) {
      int c = n0 + wn + ni * 16 + l16;
      float bsv = bias[c];
#pragma unroll
      for (int reg = 0; reg < 4; reg++) {
        int r = m0 + wm + mi * 16 + quad * 4 + reg;
        float v = acc[mi][ni][reg] + bsv;
        if (EPI == 1) v = gelu_exact(v);
        if (EPI == 2) v += res[(size_t)r * ldc + c];
        if (OBF) ((short*)Cv)[(size_t)r * ldc + c] = f2b(v);
        else     ((float*)Cv)[(size_t)r * ldc + c] = v;
      }
    }
}

// ---------------- bf16 MFMA GEMM 64x64, BK=64, dbuf + 2-phase prefetch ----------------
template<int EPI, int OBF, int SWZ>
__launch_bounds__(256)
__global__ void gemm_bf16_64(const short* __restrict__ A, const short* __restrict__ Bt,
                             const float* __restrict__ bias, const float* __restrict__ res,
                             void* __restrict__ Cv, int ldc, int K) {
  __shared__ short As[2][64 * 64];   // 16 KB
  __shared__ short Bs[2][64 * 64];   // 16 KB
  int tid = threadIdx.x;
  int bx = blockIdx.x, by = blockIdx.y;
  if (SWZ) xcd_remap(bx, by);
  int n0 = bx * 64, m0 = by * 64;
  int lr = tid >> 3;
  int lc = (((tid & 7) ^ (lr & 7)) * 8);
  int wid = tid >> 6, lane = tid & 63;
  int wm = (wid & 1) * 32, wn = (wid >> 1) * 32;
  int quad = lane >> 4, l16 = lane & 15;
  f32x4 acc[2][2];
#pragma unroll
  for (int i = 0; i < 2; i++)
#pragma unroll
    for (int j = 0; j < 2; j++) acc[i][j] = (f32x4){0.f, 0.f, 0.f, 0.f};

  const short* ga = A + (size_t)(m0 + lr) * K + lc;
  const short* gb = Bt + (size_t)(n0 + lr) * K + lc;
  short* la = &As[0][tid * 8];     // buffer stride 4096 shorts
  short* lb = &Bs[0][tid * 8];

#pragma unroll
  for (int r = 0; r < 2; r++) {
    gload16(ga + (size_t)(r * 32) * K, la + r * 2048);
    gload16(gb + (size_t)(r * 32) * K, lb + r * 2048);
  }
  asm volatile("s_waitcnt vmcnt(0)" ::: "memory");
  __builtin_amdgcn_s_barrier();

  int NT = K >> 6;
  for (int t = 0; t < NT; ++t) {
    int cur = t & 1;
    if (t + 1 < NT) {
      int nb = (cur ^ 1) * 4096;
      int k1 = (t + 1) << 6;
#pragma unroll
      for (int r = 0; r < 2; r++) {
        gload16(ga + (size_t)(r * 32) * K + k1, la + nb + r * 2048);
        gload16(gb + (size_t)(r * 32) * K + k1, lb + nb + r * 2048);
      }
    }
#pragma unroll
    for (int kk = 0; kk < 2; kk++) {
      bfrag af[2], bfv[2];
#pragma unroll
      for (int mi = 0; mi < 2; mi++) {
        int row = wm + mi * 16 + l16;
        af[mi] = *reinterpret_cast<const bfrag*>(
            &As[cur][row * 64 + (((kk * 4 + quad) ^ (row & 7)) * 8)]);
      }
#pragma unroll
      for (int ni = 0; ni < 2; ni++) {
        int row = wn + ni * 16 + l16;
        bfv[ni] = *reinterpret_cast<const bfrag*>(
            &Bs[cur][row * 64 + (((kk * 4 + quad) ^ (row & 7)) * 8)]);
      }
#pragma unroll
      for (int mi = 0; mi < 2; mi++)
#pragma unroll
        for (int ni = 0; ni < 2; ni++)
          acc[mi][ni] = __builtin_amdgcn_mfma_f32_16x16x32_bf16(af[mi], bfv[ni], acc[mi][ni], 0, 0, 0);
    }
    asm volatile("s_waitcnt vmcnt(0)" ::: "memory");
    __builtin_amdgcn_s_barrier();
  }

#pragma unroll
  for (int mi = 0; mi < 2; mi++)
#pragma unroll
    for (int ni = 0; ni < 2; ni++) {
      int c = n0 + wn + ni * 16 + l16;
      float bsv = bias[c];
#pragma unroll
      for (int reg = 0; reg < 4; reg++) {
        int r = m0 + wm + mi * 16 + quad * 4 + reg;
        float v = acc[mi][ni][reg] + bsv;
        if (EPI == 1) v = gelu_exact(v);
        if (EPI == 2) v += res[(size_t)r * ldc + c];
        if (OBF) ((short*)Cv)[(size_t)r * ldc + c] = f2b(v);
        else     ((float*)Cv)[(size_t)r * ldc + c] = v;
      }
    }
}

// ---------------- split-K GEMM for w2, BK=64, dbuf + 2-phase prefetch ----------------
__launch_bounds__(256)
__global__ void gemm_splitk(const short* __restrict__ A, const short* __restrict__ Bt,
                            float* __restrict__ part, int K, int Ks) {
  __shared__ short As[2][64 * 64];
  __shared__ short Bs[2][64 * 64];
  int tid = threadIdx.x;
  int n0 = blockIdx.x * 64, m0 = blockIdx.y * 64, s = blockIdx.z;
  int kbase = s * Ks;
  int lr = tid >> 3;
  int lc = (((tid & 7) ^ (lr & 7)) * 8);
  int wid = tid >> 6, lane = tid & 63;
  int wm = (wid & 1) * 32, wn = (wid >> 1) * 32;
  int quad = lane >> 4, l16 = lane & 15;
  f32x4 acc[2][2];
#pragma unroll
  for (int i = 0; i < 2; i++)
#pragma unroll
    for (int j = 0; j < 2; j++) acc[i][j] = (f32x4){0.f, 0.f, 0.f, 0.f};

  const short* ga = A + (size_t)(m0 + lr) * K + kbase + lc;
  const short* gb = Bt + (size_t)(n0 + lr) * K + kbase + lc;
  short* la = &As[0][tid * 8];
  short* lb = &Bs[0][tid * 8];

#pragma unroll
  for (int r = 0; r < 2; r++) {
    gload16(ga + (size_t)(r * 32) * K, la + r * 2048);
    gload16(gb + (size_t)(r * 32) * K, lb + r * 2048);
  }
  asm volatile("s_waitcnt vmcnt(0)" ::: "memory");
  __builtin_amdgcn_s_barrier();

  int NT = Ks >> 6;
  for (int t = 0; t < NT; ++t) {
    int cur = t & 1;
    if (t + 1 < NT) {
      int nb = (cur ^ 1) * 4096;
      int k1 = (t + 1) << 6;
#pragma unroll
      for (int r = 0; r < 2; r++) {
        gload16(ga + (size_t)(r * 32) * K + k1, la + nb + r * 2048);
        gload16(gb + (size_t)(r * 32) * K + k1, lb + nb + r * 2048);
      }
    }
#pragma unroll
    for (int kk = 0; kk < 2; kk++) {
      bfrag af[2], bfv[2];
#pragma unroll
      for (int mi = 0; mi < 2; mi++) {
        int row = wm + mi * 16 + l16;
        af[mi] = *reinterpret_cast<const bfrag*>(
            &As[cur][row * 64 + (((kk * 4 + quad) ^ (row & 7)) * 8)]);
      }
#pragma unroll
      for (int ni = 0; ni < 2; ni++) {
        int row = wn + ni * 16 + l16;
        bfv[ni] = *reinterpret_cast<const bfrag*>(
            &Bs[cur][row * 64 + (((kk * 4 + quad) ^ (row & 7)) * 8)]);
      }
#pragma unroll
      for (int mi = 0; mi < 2; mi++)
#pragma unroll
        for (int ni = 0; ni < 2; ni++)
          acc[mi][ni] = __builtin_amdgcn_mfma_f32_16x16x32_bf16(af[mi], bfv[ni], acc[mi][ni], 0, 0, 0);
    }
    asm volatile("s_waitcnt vmcnt(0)" ::: "memory");
    __builtin_amdgcn_s_barrier();
  }

#pragma unroll
  for (int mi = 0; mi < 2; mi++)
#pragma unroll
    for (int ni = 0; ni < 2; ni++) {
      int c = n0 + wn + ni * 16 + l16;
#pragma unroll
      for (int reg = 0; reg < 4; reg++) {
        int r = m0 + wm + mi * 16 + quad * 4 + reg;
        part[(size_t)s * 524288 + (size_t)r * 1024 + c] = acc[mi][ni][reg];
      }
    }
}

// reduce 4 partials + bias + residual -> patches (f32)
__global__ void w2red_kernel(const float* __restrict__ part, const float* __restrict__ bias,
                             float* __restrict__ patches) {
  int i = (blockIdx.x * 256 + threadIdx.x) * 4;  // over 512*1024 elems
  float4 v = *(const float4*)(part + i);
#pragma unroll
  for (int s = 1; s < 4; s++) {
    float4 p = *(const float4*)(part + (size_t)s * 524288 + i);
    v.x += p.x; v.y += p.y; v.z += p.z; v.w += p.w;
  }
  int c = i & 1023;
  float4 bv = *(const float4*)(bias + c);
  float4 rv = *(const float4*)(patches + i);
  v.x += bv.x + rv.x; v.y += bv.y + rv.y; v.z += bv.z + rv.z; v.w += bv.w + rv.w;
  *(float4*)(patches + i) = v;
}

// ---------------- global self-attn MFMA: nh=16, dh=64, P=256, causal ----------------
__launch_bounds__(256)
__global__ void attn_global3(const short* __restrict__ qkvb, const short* __restrict__ vtg,
                             short* __restrict__ outp) {
  int qt = blockIdx.x;
  int bh = blockIdx.y; int h = bh & 15, b = bh >> 4;
  int tid = threadIdx.x;
  int wid = tid >> 6, lane = tid & 63;
  int quad = lane >> 4, l16 = lane & 15;
  int q0 = qt * 64 + wid * 16;
  __shared__ short KV[64 * 72];
  __shared__ short Pl[4][16][264];
  const short* qrow = qkvb + ((size_t)(b * Pn + q0 + l16)) * 3072 + h * 64 + quad * 8;
  bfrag qf[2];
#pragma unroll
  for (int kd = 0; kd < 2; kd++) qf[kd] = *(const bfrag*)(qrow + kd * 32);
  f32x4 sacc[16];
#pragma unroll
  for (int n = 0; n < 16; n++) sacc[n] = (f32x4){0.f, 0.f, 0.f, 0.f};
  int cr = tid >> 2, cc = (tid & 3) * 16;
#pragma unroll
  for (int kc = 0; kc < 4; kc++) {
    if (kc <= qt) {
      const short* ksrc = qkvb + ((size_t)(b * Pn + kc * 64 + cr)) * 3072 + 1024 + h * 64 + cc;
      int4 v0 = *(const int4*)(ksrc);
      int4 v1 = *(const int4*)(ksrc + 8);
      __syncthreads();
      *(int4*)&KV[cr * 72 + cc] = v0;
      *(int4*)&KV[cr * 72 + cc + 8] = v1;
      __syncthreads();
#pragma unroll
      for (int n = 0; n < 4; n++)
#pragma unroll
        for (int kd = 0; kd < 2; kd++) {
          bfrag kf = *(const bfrag*)&KV[(n * 16 + l16) * 72 + kd * 32 + quad * 8];
          sacc[kc * 4 + n] = __builtin_amdgcn_mfma_f32_16x16x32_bf16(qf[kd], kf, sacc[kc * 4 + n], 0, 0, 0);
        }
    }
  }
  int nfr = (qt + 1) * 4;
  const float scale = 0.125f;
  float mx[4] = {-1e30f, -1e30f, -1e30f, -1e30f};
#pragma unroll
  for (int n = 0; n < 16; n++) {
    if (n < nfr) {
      int col = n * 16 + l16;
#pragma unroll
      for (int r = 0; r < 4; r++)
        if (col <= q0 + quad * 4 + r) mx[r] = fmaxf(mx[r], sacc[n][r]);
    }
  }
#pragma unroll
  for (int off = 1; off < 16; off <<= 1)
#pragma unroll
    for (int r = 0; r < 4; r++) mx[r] = fmaxf(mx[r], __shfl_xor(mx[r], off));
  float ls[4] = {0.f, 0.f, 0.f, 0.f};
#pragma unroll
  for (int n = 0; n < 16; n++) {
    if (n < nfr) {
      int col = n * 16 + l16;
#pragma unroll
      for (int r = 0; r < 4; r++) {
        float p = (col <= q0 + quad * 4 + r) ? __expf((sacc[n][r] - mx[r]) * scale) : 0.f;
        Pl[wid][quad * 4 + r][col] = f2b(p);
        ls[r] += p;
      }
    }
  }
#pragma unroll
  for (int off = 1; off < 16; off <<= 1)
#pragma unroll
    for (int r = 0; r < 4; r++) ls[r] += __shfl_xor(ls[r], off);
  float rl[4];
#pragma unroll
  for (int r = 0; r < 4; r++) rl[r] = 1.0f / ls[r];

  f32x4 oacc[4];
#pragma unroll
  for (int n = 0; n < 4; n++) oacc[n] = (f32x4){0.f, 0.f, 0.f, 0.f};
#pragma unroll
  for (int kc = 0; kc < 4; kc++) {
    if (kc <= qt) {
      const short* vsrc = vtg + (size_t)bh * 64 * 256 + cr * 256 + kc * 64 + cc;
      int4 v0 = *(const int4*)(vsrc);
      int4 v1 = *(const int4*)(vsrc + 8);
      __syncthreads();
      *(int4*)&KV[cr * 72 + cc] = v0;
      *(int4*)&KV[cr * 72 + cc + 8] = v1;
      __syncthreads();
#pragma unroll
      for (int kk = 0; kk < 2; kk++) {
        bfrag pa = *(const bfrag*)&Pl[wid][l16][kc * 64 + kk * 32 + quad * 8];
#pragma unroll
        for (int n = 0; n < 4; n++) {
          bfrag vf = *(const bfrag*)&KV[(n * 16 + l16) * 72 + kk * 32 + quad * 8];
          oacc[n] = __builtin_amdgcn_mfma_f32_16x16x32_bf16(pa, vf, oacc[n], 0, 0, 0);
        }
      }
    }
  }
#pragma unroll
  for (int n = 0; n < 4; n++)
#pragma unroll
    for (int r = 0; r < 4; r++)
      outp[(size_t)(b * Pn + q0 + quad * 4 + r) * Hdim + h * 64 + n * 16 + l16] = f2b(oacc[n][r] * rl[r]);
}

// ---------------- cross-attn MFMA v4: LDS-staged K/V chunks. nh=8, dh=128, Lq=4096, Lk=256 ----------------
__launch_bounds__(256)
__global__ void attn_cross4(const short* __restrict__ q, const short* __restrict__ k,
                            const short* __restrict__ vt, short* __restrict__ outp) {
  int bh = blockIdx.y; int h = bh & 7, b = bh >> 3;
  int tid = threadIdx.x;
  int wid = tid >> 6, lane = tid & 63;
  int quad = lane >> 4, l16 = lane & 15;
  int q0 = blockIdx.x * 64 + wid * 16;
  __shared__ short KV[9216];
  __shared__ short Pl[4][16][264];
  const short* qrow = q + ((size_t)(b * Slen + q0 + l16)) * Hdim + h * 128 + quad * 8;
  bfrag qf[4];
#pragma unroll
  for (int kd = 0; kd < 4; kd++) qf[kd] = *(const bfrag*)(qrow + kd * 32);
  f32x4 sacc[16];
#pragma unroll
  for (int n = 0; n < 16; n++) sacc[n] = (f32x4){0.f, 0.f, 0.f, 0.f};

  int cr4 = tid >> 2, cc4 = (tid & 3) * 32;
#pragma unroll
  for (int kc = 0; kc < 4; kc++) {
    const short* ksrc = k + ((size_t)(b * Pn + kc * 64 + cr4)) * Hdim + h * 128 + cc4;
    int4 v0 = *(const int4*)(ksrc);
    int4 v1 = *(const int4*)(ksrc + 8);
    int4 v2 = *(const int4*)(ksrc + 16);
    int4 v3 = *(const int4*)(ksrc + 24);
    __syncthreads();
    *(int4*)&KV[cr4 * 136 + cc4]      = v0;
    *(int4*)&KV[cr4 * 136 + cc4 + 8]  = v1;
    *(int4*)&KV[cr4 * 136 + cc4 + 16] = v2;
    *(int4*)&KV[cr4 * 136 + cc4 + 24] = v3;
    __syncthreads();
#pragma unroll
    for (int n = 0; n < 4; n++)
#pragma unroll
      for (int kd = 0; kd < 4; kd++) {
        bfrag kf = *(const bfrag*)&KV[(n * 16 + l16) * 136 + kd * 32 + quad * 8];
        sacc[kc * 4 + n] = __builtin_amdgcn_mfma_f32_16x16x32_bf16(qf[kd], kf, sacc[kc * 4 + n], 0, 0, 0);
      }
  }

  const float scale = 0.088388347648318447f;
  float mx[4] = {-1e30f, -1e30f, -1e30f, -1e30f};
#pragma unroll
  for (int n = 0; n < 16; n++)
#pragma unroll
    for (int r = 0; r < 4; r++) mx[r] = fmaxf(mx[r], sacc[n][r]);
#pragma unroll
  for (int off = 1; off < 16; off <<= 1)
#pragma unroll
    for (int r = 0; r < 4; r++) mx[r] = fmaxf(mx[r], __shfl_xor(mx[r], off));
  float ls[4] = {0.f, 0.f, 0.f, 0.f};
#pragma unroll
  for (int n = 0; n < 16; n++)
#pragma unroll
    for (int r = 0; r < 4; r++) {
      float p = __expf((sacc[n][r] - mx[r]) * scale);
      Pl[wid][quad * 4 + r][n * 16 + l16] = f2b(p);
      ls[r] += p;
    }
#pragma unroll
  for (int off = 1; off < 16; off <<= 1)
#pragma unroll
    for (int r = 0; r < 4; r++) ls[r] += __shfl_xor(ls[r], off);
  float rl[4];
#pragma unroll
  for (int r = 0; r < 4; r++) rl[r] = 1.0f / ls[r];

  f32x4 oacc[8];
#pragma unroll
  for (int n = 0; n < 8; n++) oacc[n] = (f32x4){0.f, 0.f, 0.f, 0.f};
  int cr2 = tid >> 1, cc2 = (tid & 1) * 32;
#pragma unroll
  for (int kc = 0; kc < 4; kc++) {
    const short* vsrc = vt + (size_t)bh * 32768 + cr2 * 256 + kc * 64 + cc2;
    int4 v0 = *(const int4*)(vsrc);
    int4 v1 = *(const int4*)(vsrc + 8);
    int4 v2 = *(const int4*)(vsrc + 16);
    int4 v3 = *(const int4*)(vsrc + 24);
    __syncthreads();
    *(int4*)&KV[cr2 * 72 + cc2]      = v0;
    *(int4*)&KV[cr2 * 72 + cc2 + 8]  = v1;
    *(int4*)&KV[cr2 * 72 + cc2 + 16] = v2;
    *(int4*)&KV[cr2 * 72 + cc2 + 24] = v3;
    __syncthreads();
#pragma unroll
    for (int kk = 0; kk < 2; kk++) {
      bfrag pa = *(const bfrag*)&Pl[wid][l16][kc * 64 + kk * 32 + quad * 8];
#pragma unroll
      for (int n = 0; n < 8; n++) {
        bfrag vf = *(const bfrag*)&KV[(n * 16 + l16) * 72 + kk * 32 + quad * 8];
        oacc[n] = __builtin_amdgcn_mfma_f32_16x16x32_bf16(pa, vf, oacc[n], 0, 0, 0);
      }
    }
  }
#pragma unroll
  for (int n = 0; n < 8; n++)
#pragma unroll
    for (int r = 0; r < 4; r++)
      outp[(size_t)(b * Slen + q0 + quad * 4 + r) * Hdim + h * 128 + n * 16 + l16] = f2b(oacc[n][r] * rl[r]);
}

extern "C" void kernel_launch(void* const* d_in, const int* in_sizes, int n_in,
                              void* d_out, int out_size, void* d_ws, size_t ws_size,
                              hipStream_t stream) {
  const int*   byte_seq = (const int*)d_in[0];
  const int*   pbound   = (const int*)d_in[1];
  const float* emb      = (const float*)d_in[2];
  const float* g_ln1_g  = (const float*)d_in[3];
  const float* g_ln1_b  = (const float*)d_in[4];
  const float* g_wqkv   = (const float*)d_in[5];
  const float* g_bqkv   = (const float*)d_in[6];
  const float* g_wo     = (const float*)d_in[7];
  const float* g_bo     = (const float*)d_in[8];
  const float* g_ln2_g  = (const float*)d_in[9];
  const float* g_ln2_b  = (const float*)d_in[10];
  const float* g_w1     = (const float*)d_in[11];
  const float* g_b1     = (const float*)d_in[12];
  const float* g_w2     = (const float*)d_in[13];
  const float* g_b2     = (const float*)d_in[14];
  const float* fn_g     = (const float*)d_in[15];
  const float* fn_b     = (const float*)d_in[16];
  const float* ca_ln_g  = (const float*)d_in[17];
  const float* ca_ln_b  = (const float*)d_in[18];
  const float* ca_wqkv  = (const float*)d_in[19];
  const float* ca_bqkv  = (const float*)d_in[20];
  const float* ca_wo    = (const float*)d_in[21];
  const float* ca_bo    = (const float*)d_in[22];
  const float* head_w   = (const float*)d_in[23];
  const float* head_b   = (const float*)d_in[24];
  float* out = (float*)d_out;

  // ---- workspace layout ----
  float* x       = (float*)d_ws;                 // 8388608 f32
  float* patches = x + 8388608;                  // 524288
  float* vbuf    = patches + 524288;             // 524288
  float* w2part  = vbuf + 524288;                // 2097152 (4 x 512x1024 partials)
  int*   pid     = (int*)(w2part + 2097152);     // 8192 ints
  short* nbuf    = (short*)(pid + 8192);         // 524288 bf16
  short* attn_o  = nbuf + 524288;                // 524288
  short* mid     = attn_o + 524288;              // 2097152
  short* qn      = mid + 2097152;                // 8388608 (LN(x); reused as caout)
  short* qb      = qn + 8388608;                 // 8388608
  short* xb      = qb + 8388608;                 // 8388608
  short* kb      = xb + 8388608;                 // 524288 (cross K bf16)
  short* vt      = kb + 524288;                  // 524288 (cross V^T bf16)
  short* qkvb    = vt + 524288;                  // 1572864 (layer qkv bf16)
  short* vtg     = qkvb + 1572864;               // 524288 (global V^T bf16)
  short* wqkv_t  = vtg + 524288;                 // 12582912
  short* wo_t    = wqkv_t + 12582912;            // 4194304
  short* w1_t    = wo_t + 4194304;               // 16777216
  short* w2_t    = w1_t + 16777216;              // 16777216
  short* caq_t   = w2_t + 16777216;              // 1048576
  short* cak_t   = caq_t + 1048576;              // 1048576
  short* cav_t   = cak_t + 1048576;              // 1048576
  short* cawo_t  = cav_t + 1048576;              // 1048576
  short* head_t  = cawo_t + 1048576;             // 262144
  short* caout   = qn;                           // alias (qn dead after q-proj)

  // 1. byte embeddings (+fused cross-attn q LayerNorm), patch ids, pooling
  embed_ln_kernel<<<Bsz * Slen, 256, 0, stream>>>(byte_seq, emb, ca_ln_g, ca_ln_b, x, qn);
  pid_kernel<<<(Bsz * Slen) / 256, 256, 0, stream>>>(pbound, pid);
  pool_kernel<<<Bsz * Pn, 256, 0, stream>>>(x, pid, patches);

  // 2. weight convert + transpose to bf16 [N,K]
  wconv_kernel<<<dim3(96, 32, 4), 256, 0, stream>>>(g_wqkv, wqkv_t, 3072, 1024, 3145728, 3145728);
  wconv_kernel<<<dim3(32, 32, 4), 256, 0, stream>>>(g_wo, wo_t, 1024, 1024, 1048576, 1048576);
  wconv_kernel<<<dim3(128, 32, 4), 256, 0, stream>>>(g_w1, w1_t, 4096, 1024, 4194304, 4194304);
  wconv_kernel<<<dim3(32, 128, 4), 256, 0, stream>>>(g_w2, w2_t, 1024, 4096, 4194304, 4194304);
  wconv_kernel<<<dim3(32, 32, 3), 256, 0, stream>>>(ca_wqkv, caq_t, 3072, 1024, 1024, 1048576);
  wconv_kernel<<<dim3(32, 32, 1), 256, 0, stream>>>(ca_wo, cawo_t, 1024, 1024, 0, 0);
  wconv_kernel<<<dim3(8, 32, 1), 256, 0, stream>>>(head_w, head_t, 256, 1024, 0, 0);

  // 3. global transformer layers
  for (int l = 0; l < NLAY; ++l) {
    ln_kernel<1><<<Bsz * Pn, 256, 0, stream>>>(patches, g_ln1_g + l * Hdim, g_ln1_b + l * Hdim, nbuf);
    gemm_bf16_64<0, 1, 0><<<dim3(48, 8), 256, 0, stream>>>(
        nbuf, wqkv_t + (size_t)l * 3145728, g_bqkv + l * 3072, nullptr, qkvb, 3072, 1024);
    vtg_kernel<<<dim3(8, 2, 32), 256, 0, stream>>>(qkvb, vtg);
    attn_global3<<<dim3(4, 32), 256, 0, stream>>>(qkvb, vtg, attn_o);
    gemm_bf16_64<2, 0, 0><<<dim3(16, 8), 256, 0, stream>>>(
        attn_o, wo_t + (size_t)l * 1048576, g_bo + l * Hdim, patches, patches, 1024, 1024);
    ln_kernel<1><<<Bsz * Pn, 256, 0, stream>>>(patches, g_ln2_g + l * Hdim, g_ln2_b + l * Hdim, nbuf);
    gemm_bf16_64<1, 1, 0><<<dim3(64, 8), 256, 0, stream>>>(
        nbuf, w1_t + (size_t)l * 4194304, g_b1 + l * 4096, nullptr, mid, 4096, 1024);
    gemm_splitk<<<dim3(16, 8, 4), 256, 0, stream>>>(
        mid, w2_t + (size_t)l * 4194304, w2part, 4096, 1024);
    w2red_kernel<<<512, 256, 0, stream>>>(w2part, g_b2 + l * Hdim, patches);
  }

  // 4. final norm (f32, in-place), then cross-attn LN of patches -> bf16
  ln_kernel<0><<<Bsz * Pn, 256, 0, stream>>>(patches, fn_g, fn_b, patches);
  ln_kernel<1><<<Bsz * Pn, 256, 0, stream>>>(patches, ca_ln_g, ca_ln_b, nbuf);

  // 5. k (bf16 out), v (f32 out -> transposed bf16)
  gemm_bf16_64<0, 1, 0><<<dim3(16, 8), 256, 0, stream>>>(
      nbuf, cak_t, ca_bqkv + 1024, nullptr, kb, 1024, 1024);
  gemm_bf16_64<0, 0, 0><<<dim3(16, 8), 256, 0, stream>>>(
      nbuf, cav_t, ca_bqkv + 2048, nullptr, vbuf, 1024, 1024);
  vt_kernel<<<dim3(8, 4, 16), 256, 0, stream>>>(vbuf, vt);

  // 6. q projection from fused LN(x) -> bf16 (M=8192: swizzle for A-panel L2 reuse)
  gemm_bf16<0, 1, 1><<<dim3(8, 64), 256, 0, stream>>>(
      qn, caq_t, ca_bqkv, nullptr, qb, 1024, 1024);

  // 7. MFMA cross attention (qn dead; caout aliases it)
  attn_cross4<<<dim3(64, 16), 256, 0, stream>>>(qb, kb, vt, caout);

  // 8. output projection + residual -> xb (bf16, feeds head)
  gemm_bf16<2, 1, 1><<<dim3(8, 64), 256, 0, stream>>>(
      caout, cawo_t, ca_bo, x, xb, 1024, 1024);

  // 9. head (M=8192: swizzle)
  gemm_bf16_64<0, 0, 1><<<dim3(4, 128), 256, 0, stream>>>(
      xb, head_t, head_b, nullptr, out, 256, 1024);
}

// Round 5
// 768.707 us; speedup vs baseline: 1.0822x; 1.0036x over previous
//
#include <hip/hip_runtime.h>
#include <hip/hip_bf16.h>
#include <math.h>

#define Hdim 1024
#define Bsz  2
#define Slen 4096
#define Pn   256
#define NLAY 4

typedef __attribute__((ext_vector_type(8))) __bf16 bfrag;
typedef __attribute__((ext_vector_type(4))) float  f32x4;

__device__ __forceinline__ float gelu_exact(float x) {
  return 0.5f * x * (1.0f + erff(x * 0.70710678118654752f));
}
__device__ __forceinline__ short f2b(float x) {
  __hip_bfloat16 h = __float2bfloat16(x);
  return *reinterpret_cast<short*>(&h);
}
// async global->LDS DMA, 16B per lane. LDS dest is wave-uniform base + lane*16,
// so LDS layout must be linear in lane order (no padding).
__device__ __forceinline__ void gload16(const short* g, short* l) {
  __builtin_amdgcn_global_load_lds(
      (const __attribute__((address_space(1))) unsigned int*)g,
      (__attribute__((address_space(3))) unsigned int*)l, 16, 0, 0);
}
// XCD-chunk swizzle (T1, bijective when nwg % 8 == 0).
__device__ __forceinline__ void xcd_remap(int& bx, int& by) {
  int nwg = gridDim.x * gridDim.y;
  int bid = blockIdx.y * gridDim.x + blockIdx.x;
  int wg = (bid & 7) * (nwg >> 3) + (bid >> 3);
  bx = wg % gridDim.x;
  by = wg / gridDim.x;
}

// ---------------- embedding gather fused with cross-attn q LayerNorm ----------------
__global__ void embed_ln_kernel(const int* __restrict__ seq, const float* __restrict__ emb,
                                const float* __restrict__ g, const float* __restrict__ bvec,
                                float* __restrict__ x, short* __restrict__ qn) {
  int row = blockIdx.x;
  int tid = threadIdx.x;
  int tok = seq[row];
  float4 v = *(const float4*)(emb + (size_t)tok * Hdim + tid * 4);
  *(float4*)(x + (size_t)row * Hdim + tid * 4) = v;
  float s  = v.x + v.y + v.z + v.w;
  float ss = v.x * v.x + v.y * v.y + v.z * v.z + v.w * v.w;
#pragma unroll
  for (int off = 32; off; off >>= 1) { s += __shfl_xor(s, off); ss += __shfl_xor(ss, off); }
  __shared__ float rs[4], rss[4];
  int wid = tid >> 6;
  if ((tid & 63) == 0) { rs[wid] = s; rss[wid] = ss; }
  __syncthreads();
  float tot  = rs[0] + rs[1] + rs[2] + rs[3];
  float tot2 = rss[0] + rss[1] + rss[2] + rss[3];
  float mu = tot * (1.0f / Hdim);
  float var = tot2 * (1.0f / Hdim) - mu * mu;
  float rstd = rsqrtf(var + 1e-6f);
  float4 gg = *(const float4*)(g + tid * 4);
  float4 bb = *(const float4*)(bvec + tid * 4);
  short4 o;
  o.x = f2b((v.x - mu) * rstd * gg.x + bb.x);
  o.y = f2b((v.y - mu) * rstd * gg.y + bb.y);
  o.z = f2b((v.z - mu) * rstd * gg.z + bb.z);
  o.w = f2b((v.w - mu) * rstd * gg.w + bb.w);
  *(short4*)(qn + (size_t)row * Hdim + tid * 4) = o;
}

// ---------------- patch ids ----------------
__global__ void pid_kernel(const int* __restrict__ bounds, int* __restrict__ pid) {
  int i = blockIdx.x * 256 + threadIdx.x;
  int b = i >> 12;
  int s = i & (Slen - 1);
  const int* bd = bounds + b * Pn;
  int lo = 0, hi = Pn;
  while (lo < hi) { int m = (lo + hi) >> 1; if (bd[m] <= s) lo = m + 1; else hi = m; }
  pid[i] = min(lo, Pn - 1);
}

// ---------------- patch mean pooling ----------------
__global__ void pool_kernel(const float* __restrict__ x, const int* __restrict__ pid,
                            float* __restrict__ patches) {
  int bp = blockIdx.x;
  int b = bp >> 8;
  int p = bp & (Pn - 1);
  const int* pv = pid + b * Slen;
  int lo = 0, hi = Slen;
  while (lo < hi) { int m = (lo + hi) >> 1; if (pv[m] < p) lo = m + 1; else hi = m; }
  int start = lo;
  lo = 0; hi = Slen;
  while (lo < hi) { int m = (lo + hi) >> 1; if (pv[m] < p + 1) lo = m + 1; else hi = m; }
  int end = lo;
  int tid = threadIdx.x;
  float4 acc = {0.f, 0.f, 0.f, 0.f};
  for (int s = start; s < end; ++s) {
    float4 xv = *(const float4*)(x + ((size_t)(b * Slen + s)) * Hdim + tid * 4);
    acc.x += xv.x; acc.y += xv.y; acc.z += xv.z; acc.w += xv.w;
  }
  float cnt = (float)(end - start);
  float r = 1.0f / fmaxf(cnt, 1.0f);
  float4 o = {acc.x * r, acc.y * r, acc.z * r, acc.w * r};
  *(float4*)(patches + (size_t)bp * Hdim + tid * 4) = o;
}

// ---------------- LayerNorm (OBF=1 -> bf16 out) ----------------
template<int OBF>
__global__ void ln_kernel(const float* __restrict__ in, const float* __restrict__ g,
                          const float* __restrict__ bvec, void* __restrict__ outv) {
  int row = blockIdx.x;
  int tid = threadIdx.x;
  const float* xr = in + (size_t)row * Hdim;
  float4 v = *(const float4*)(xr + tid * 4);
  float s  = v.x + v.y + v.z + v.w;
  float ss = v.x * v.x + v.y * v.y + v.z * v.z + v.w * v.w;
#pragma unroll
  for (int off = 32; off; off >>= 1) { s += __shfl_xor(s, off); ss += __shfl_xor(ss, off); }
  __shared__ float rs[4], rss[4];
  int wid = tid >> 6;
  if ((tid & 63) == 0) { rs[wid] = s; rss[wid] = ss; }
  __syncthreads();
  float tot  = rs[0] + rs[1] + rs[2] + rs[3];
  float tot2 = rss[0] + rss[1] + rss[2] + rss[3];
  float mu = tot * (1.0f / Hdim);
  float var = tot2 * (1.0f / Hdim) - mu * mu;
  float rstd = rsqrtf(var + 1e-6f);
  float4 gg = *(const float4*)(g + tid * 4);
  float4 bb = *(const float4*)(bvec + tid * 4);
  float4 r;
  r.x = (v.x - mu) * rstd * gg.x + bb.x;
  r.y = (v.y - mu) * rstd * gg.y + bb.y;
  r.z = (v.z - mu) * rstd * gg.z + bb.z;
  r.w = (v.w - mu) * rstd * gg.w + bb.w;
  if (OBF) {
    short4 o; o.x = f2b(r.x); o.y = f2b(r.y); o.z = f2b(r.z); o.w = f2b(r.w);
    *(short4*)((short*)outv + (size_t)row * Hdim + tid * 4) = o;
  } else {
    *(float4*)((float*)outv + (size_t)row * Hdim + tid * 4) = r;
  }
}

// ---------------- weight convert + transpose: f32 [K,N](ldin) -> bf16 [N,K] ----------------
__global__ void wconv_kernel(const float* __restrict__ in, short* __restrict__ out,
                             int ldin, int K, size_t in_lstride, size_t out_lstride) {
  int z = blockIdx.z;
  const float* src = in + (size_t)z * in_lstride;
  short* dst = out + (size_t)z * out_lstride;
  int n0 = blockIdx.x * 32, k0 = blockIdx.y * 32;
  int tx = threadIdx.x & 31, ty = threadIdx.x >> 5;
  __shared__ float t[32][33];
#pragma unroll
  for (int i = 0; i < 4; i++)
    t[ty + 8 * i][tx] = src[(size_t)(k0 + ty + 8 * i) * ldin + n0 + tx];
  __syncthreads();
#pragma unroll
  for (int i = 0; i < 4; i++)
    dst[(size_t)(n0 + ty + 8 * i) * K + k0 + tx] = f2b(t[tx][ty + 8 * i]);
}

// ---------------- V transpose for cross attention: f32 [b,key,h*128+d] -> bf16 [bh][d][key] ----------------
__global__ void vt_kernel(const float* __restrict__ in, short* __restrict__ out) {
  int bh = blockIdx.z; int h = bh & 7; int b = bh >> 3;
  int kk0 = blockIdx.x * 32, d0 = blockIdx.y * 32;
  int tx = threadIdx.x & 31, ty = threadIdx.x >> 5;
  __shared__ float t[32][33];
  const float* src = in + (size_t)b * Pn * Hdim + h * 128;
#pragma unroll
  for (int i = 0; i < 4; i++)
    t[ty + 8 * i][tx] = src[(size_t)(kk0 + ty + 8 * i) * Hdim + d0 + tx];
  __syncthreads();
  short* dst = out + (size_t)bh * 128 * 256;
#pragma unroll
  for (int i = 0; i < 4; i++)
    dst[(size_t)(d0 + ty + 8 * i) * 256 + kk0 + tx] = f2b(t[tx][ty + 8 * i]);
}

// ---------------- V^T for global attn: bf16 qkv [b,key,3072] (v at 2048+h*64) -> [bh][d=64][key=256] ----------------
__global__ void vtg_kernel(const short* __restrict__ qkvb, short* __restrict__ out) {
  int bh = blockIdx.z; int h = bh & 15; int b = bh >> 4;
  int kk0 = blockIdx.x * 32, d0 = blockIdx.y * 32;
  int tx = threadIdx.x & 31, ty = threadIdx.x >> 5;
  __shared__ short t[32][33];
  const short* src = qkvb + (size_t)b * Pn * 3072 + 2048 + h * 64;
#pragma unroll
  for (int i = 0; i < 4; i++)
    t[ty + 8 * i][tx] = src[(size_t)(kk0 + ty + 8 * i) * 3072 + d0 + tx];
  __syncthreads();
  short* dst = out + (size_t)bh * 64 * 256;
#pragma unroll
  for (int i = 0; i < 4; i++)
    dst[(size_t)(d0 + ty + 8 * i) * 256 + kk0 + tx] = t[tx][ty + 8 * i];
}

// ---------------- bf16 MFMA GEMM 128x128, BK=64, dbuf LDS + 2-phase prefetch ----------------
template<int EPI, int OBF, int SWZ>
__launch_bounds__(256)
__global__ void gemm_bf16(const short* __restrict__ A, const short* __restrict__ Bt,
                          const float* __restrict__ bias, const float* __restrict__ res,
                          void* __restrict__ Cv, int ldc, int K) {
  __shared__ short As[2][128 * 64];   // 32 KB
  __shared__ short Bs[2][128 * 64];   // 32 KB
  int tid = threadIdx.x;
  int bx = blockIdx.x, by = blockIdx.y;
  if (SWZ) xcd_remap(bx, by);
  int n0 = bx * 128, m0 = by * 128;
  int lr = tid >> 3;                       // 0..31 (staging row within round)
  int lc = (((tid & 7) ^ (lr & 7)) * 8);   // pre-swizzled source chunk
  int wid = tid >> 6, lane = tid & 63;
  int wm = (wid & 1) * 64, wn = (wid >> 1) * 64;
  int quad = lane >> 4, l16 = lane & 15;
  f32x4 acc[4][4];
#pragma unroll
  for (int i = 0; i < 4; i++)
#pragma unroll
    for (int j = 0; j < 4; j++) acc[i][j] = (f32x4){0.f, 0.f, 0.f, 0.f};

  const short* ga = A + (size_t)(m0 + lr) * K + lc;
  const short* gb = Bt + (size_t)(n0 + lr) * K + lc;
  short* la = &As[0][tid * 8];     // linear DMA dest; buffer stride 8192 shorts
  short* lb = &Bs[0][tid * 8];

#pragma unroll
  for (int r = 0; r < 4; r++) {
    gload16(ga + (size_t)(r * 32) * K, la + r * 2048);
    gload16(gb + (size_t)(r * 32) * K, lb + r * 2048);
  }
  asm volatile("s_waitcnt vmcnt(0)" ::: "memory");
  __builtin_amdgcn_s_barrier();

  int NT = K >> 6;
  for (int t = 0; t < NT; ++t) {
    int cur = t & 1;
    if (t + 1 < NT) {
      int nb = (cur ^ 1) * 8192;
      int k1 = (t + 1) << 6;
#pragma unroll
      for (int r = 0; r < 4; r++) {
        gload16(ga + (size_t)(r * 32) * K + k1, la + nb + r * 2048);
        gload16(gb + (size_t)(r * 32) * K + k1, lb + nb + r * 2048);
      }
    }
#pragma unroll
    for (int kk = 0; kk < 2; kk++) {
      bfrag af[4], bfv[4];
#pragma unroll
      for (int mi = 0; mi < 4; mi++) {
        int row = wm + mi * 16 + l16;
        af[mi] = *reinterpret_cast<const bfrag*>(
            &As[cur][row * 64 + (((kk * 4 + quad) ^ (row & 7)) * 8)]);
      }
#pragma unroll
      for (int ni = 0; ni < 4; ni++) {
        int row = wn + ni * 16 + l16;
        bfv[ni] = *reinterpret_cast<const bfrag*>(
            &Bs[cur][row * 64 + (((kk * 4 + quad) ^ (row & 7)) * 8)]);
      }
#pragma unroll
      for (int mi = 0; mi < 4; mi++)
#pragma unroll
        for (int ni = 0; ni < 4; ni++)
          acc[mi][ni] = __builtin_amdgcn_mfma_f32_16x16x32_bf16(af[mi], bfv[ni], acc[mi][ni], 0, 0, 0);
    }
    asm volatile("s_waitcnt vmcnt(0)" ::: "memory");
    __builtin_amdgcn_s_barrier();
  }

#pragma unroll
  for (int mi = 0; mi < 4; mi++)
#pragma unroll
    for (int ni = 0; ni < 4; ni++) {
      int c = n0 + wn + ni * 16 + l16;
      float bsv = bias[c];
#pragma unroll
      for (int reg = 0; reg < 4; reg++) {
        int r = m0 + wm + mi * 16 + quad * 4 + reg;
        float v = acc[mi][ni][reg] + bsv;
        if (EPI == 1) v = gelu_exact(v);
        if (EPI == 2) v += res[(size_t)r * ldc + c];
        if (OBF) ((short*)Cv)[(size_t)r * ldc + c] = f2b(v);
        else     ((float*)Cv)[(size_t)r * ldc + c] = v;
      }
    }
}

// ---------------- bf16 MFMA GEMM 64x64, BK=64, dbuf + 2-phase prefetch ----------------
template<int EPI, int OBF, int SWZ>
__launch_bounds__(256)
__global__ void gemm_bf16_64(const short* __restrict__ A, const short* __restrict__ Bt,
                             const float* __restrict__ bias, const float* __restrict__ res,
                             void* __restrict__ Cv, int ldc, int K) {
  __shared__ short As[2][64 * 64];   // 16 KB
  __shared__ short Bs[2][64 * 64];   // 16 KB
  int tid = threadIdx.x;
  int bx = blockIdx.x, by = blockIdx.y;
  if (SWZ) xcd_remap(bx, by);
  int n0 = bx * 64, m0 = by * 64;
  int lr = tid >> 3;
  int lc = (((tid & 7) ^ (lr & 7)) * 8);
  int wid = tid >> 6, lane = tid & 63;
  int wm = (wid & 1) * 32, wn = (wid >> 1) * 32;
  int quad = lane >> 4, l16 = lane & 15;
  f32x4 acc[2][2];
#pragma unroll
  for (int i = 0; i < 2; i++)
#pragma unroll
    for (int j = 0; j < 2; j++) acc[i][j] = (f32x4){0.f, 0.f, 0.f, 0.f};

  const short* ga = A + (size_t)(m0 + lr) * K + lc;
  const short* gb = Bt + (size_t)(n0 + lr) * K + lc;
  short* la = &As[0][tid * 8];     // buffer stride 4096 shorts
  short* lb = &Bs[0][tid * 8];

#pragma unroll
  for (int r = 0; r < 2; r++) {
    gload16(ga + (size_t)(r * 32) * K, la + r * 2048);
    gload16(gb + (size_t)(r * 32) * K, lb + r * 2048);
  }
  asm volatile("s_waitcnt vmcnt(0)" ::: "memory");
  __builtin_amdgcn_s_barrier();

  int NT = K >> 6;
  for (int t = 0; t < NT; ++t) {
    int cur = t & 1;
    if (t + 1 < NT) {
      int nb = (cur ^ 1) * 4096;
      int k1 = (t + 1) << 6;
#pragma unroll
      for (int r = 0; r < 2; r++) {
        gload16(ga + (size_t)(r * 32) * K + k1, la + nb + r * 2048);
        gload16(gb + (size_t)(r * 32) * K + k1, lb + nb + r * 2048);
      }
    }
#pragma unroll
    for (int kk = 0; kk < 2; kk++) {
      bfrag af[2], bfv[2];
#pragma unroll
      for (int mi = 0; mi < 2; mi++) {
        int row = wm + mi * 16 + l16;
        af[mi] = *reinterpret_cast<const bfrag*>(
            &As[cur][row * 64 + (((kk * 4 + quad) ^ (row & 7)) * 8)]);
      }
#pragma unroll
      for (int ni = 0; ni < 2; ni++) {
        int row = wn + ni * 16 + l16;
        bfv[ni] = *reinterpret_cast<const bfrag*>(
            &Bs[cur][row * 64 + (((kk * 4 + quad) ^ (row & 7)) * 8)]);
      }
#pragma unroll
      for (int mi = 0; mi < 2; mi++)
#pragma unroll
        for (int ni = 0; ni < 2; ni++)
          acc[mi][ni] = __builtin_amdgcn_mfma_f32_16x16x32_bf16(af[mi], bfv[ni], acc[mi][ni], 0, 0, 0);
    }
    asm volatile("s_waitcnt vmcnt(0)" ::: "memory");
    __builtin_amdgcn_s_barrier();
  }

#pragma unroll
  for (int mi = 0; mi < 2; mi++)
#pragma unroll
    for (int ni = 0; ni < 2; ni++) {
      int c = n0 + wn + ni * 16 + l16;
      float bsv = bias[c];
#pragma unroll
      for (int reg = 0; reg < 4; reg++) {
        int r = m0 + wm + mi * 16 + quad * 4 + reg;
        float v = acc[mi][ni][reg] + bsv;
        if (EPI == 1) v = gelu_exact(v);
        if (EPI == 2) v += res[(size_t)r * ldc + c];
        if (OBF) ((short*)Cv)[(size_t)r * ldc + c] = f2b(v);
        else     ((float*)Cv)[(size_t)r * ldc + c] = v;
      }
    }
}

// ---------------- split-K GEMM for w2, BK=64, dbuf + 2-phase prefetch ----------------
__launch_bounds__(256)
__global__ void gemm_splitk(const short* __restrict__ A, const short* __restrict__ Bt,
                            float* __restrict__ part, int K, int Ks) {
  __shared__ short As[2][64 * 64];
  __shared__ short Bs[2][64 * 64];
  int tid = threadIdx.x;
  int n0 = blockIdx.x * 64, m0 = blockIdx.y * 64, s = blockIdx.z;
  int kbase = s * Ks;
  int lr = tid >> 3;
  int lc = (((tid & 7) ^ (lr & 7)) * 8);
  int wid = tid >> 6, lane = tid & 63;
  int wm = (wid & 1) * 32, wn = (wid >> 1) * 32;
  int quad = lane >> 4, l16 = lane & 15;
  f32x4 acc[2][2];
#pragma unroll
  for (int i = 0; i < 2; i++)
#pragma unroll
    for (int j = 0; j < 2; j++) acc[i][j] = (f32x4){0.f, 0.f, 0.f, 0.f};

  const short* ga = A + (size_t)(m0 + lr) * K + kbase + lc;
  const short* gb = Bt + (size_t)(n0 + lr) * K + kbase + lc;
  short* la = &As[0][tid * 8];
  short* lb = &Bs[0][tid * 8];

#pragma unroll
  for (int r = 0; r < 2; r++) {
    gload16(ga + (size_t)(r * 32) * K, la + r * 2048);
    gload16(gb + (size_t)(r * 32) * K, lb + r * 2048);
  }
  asm volatile("s_waitcnt vmcnt(0)" ::: "memory");
  __builtin_amdgcn_s_barrier();

  int NT = Ks >> 6;
  for (int t = 0; t < NT; ++t) {
    int cur = t & 1;
    if (t + 1 < NT) {
      int nb = (cur ^ 1) * 4096;
      int k1 = (t + 1) << 6;
#pragma unroll
      for (int r = 0; r < 2; r++) {
        gload16(ga + (size_t)(r * 32) * K + k1, la + nb + r * 2048);
        gload16(gb + (size_t)(r * 32) * K + k1, lb + nb + r * 2048);
      }
    }
#pragma unroll
    for (int kk = 0; kk < 2; kk++) {
      bfrag af[2], bfv[2];
#pragma unroll
      for (int mi = 0; mi < 2; mi++) {
        int row = wm + mi * 16 + l16;
        af[mi] = *reinterpret_cast<const bfrag*>(
            &As[cur][row * 64 + (((kk * 4 + quad) ^ (row & 7)) * 8)]);
      }
#pragma unroll
      for (int ni = 0; ni < 2; ni++) {
        int row = wn + ni * 16 + l16;
        bfv[ni] = *reinterpret_cast<const bfrag*>(
            &Bs[cur][row * 64 + (((kk * 4 + quad) ^ (row & 7)) * 8)]);
      }
#pragma unroll
      for (int mi = 0; mi < 2; mi++)
#pragma unroll
        for (int ni = 0; ni < 2; ni++)
          acc[mi][ni] = __builtin_amdgcn_mfma_f32_16x16x32_bf16(af[mi], bfv[ni], acc[mi][ni], 0, 0, 0);
    }
    asm volatile("s_waitcnt vmcnt(0)" ::: "memory");
    __builtin_amdgcn_s_barrier();
  }

#pragma unroll
  for (int mi = 0; mi < 2; mi++)
#pragma unroll
    for (int ni = 0; ni < 2; ni++) {
      int c = n0 + wn + ni * 16 + l16;
#pragma unroll
      for (int reg = 0; reg < 4; reg++) {
        int r = m0 + wm + mi * 16 + quad * 4 + reg;
        part[(size_t)s * 524288 + (size_t)r * 1024 + c] = acc[mi][ni][reg];
      }
    }
}

// reduce 4 partials + bias + residual -> patches (f32)
__global__ void w2red_kernel(const float* __restrict__ part, const float* __restrict__ bias,
                             float* __restrict__ patches) {
  int i = (blockIdx.x * 256 + threadIdx.x) * 4;  // over 512*1024 elems
  float4 v = *(const float4*)(part + i);
#pragma unroll
  for (int s = 1; s < 4; s++) {
    float4 p = *(const float4*)(part + (size_t)s * 524288 + i);
    v.x += p.x; v.y += p.y; v.z += p.z; v.w += p.w;
  }
  int c = i & 1023;
  float4 bv = *(const float4*)(bias + c);
  float4 rv = *(const float4*)(patches + i);
  v.x += bv.x + rv.x; v.y += bv.y + rv.y; v.z += bv.z + rv.z; v.w += bv.w + rv.w;
  *(float4*)(patches + i) = v;
}

// ---------------- global self-attn MFMA: nh=16, dh=64, P=256, causal ----------------
__launch_bounds__(256)
__global__ void attn_global3(const short* __restrict__ qkvb, const short* __restrict__ vtg,
                             short* __restrict__ outp) {
  int qt = blockIdx.x;
  int bh = blockIdx.y; int h = bh & 15, b = bh >> 4;
  int tid = threadIdx.x;
  int wid = tid >> 6, lane = tid & 63;
  int quad = lane >> 4, l16 = lane & 15;
  int q0 = qt * 64 + wid * 16;
  __shared__ short KV[64 * 72];
  __shared__ short Pl[4][16][264];
  const short* qrow = qkvb + ((size_t)(b * Pn + q0 + l16)) * 3072 + h * 64 + quad * 8;
  bfrag qf[2];
#pragma unroll
  for (int kd = 0; kd < 2; kd++) qf[kd] = *(const bfrag*)(qrow + kd * 32);
  f32x4 sacc[16];
#pragma unroll
  for (int n = 0; n < 16; n++) sacc[n] = (f32x4){0.f, 0.f, 0.f, 0.f};
  int cr = tid >> 2, cc = (tid & 3) * 16;
#pragma unroll
  for (int kc = 0; kc < 4; kc++) {
    if (kc <= qt) {
      const short* ksrc = qkvb + ((size_t)(b * Pn + kc * 64 + cr)) * 3072 + 1024 + h * 64 + cc;
      int4 v0 = *(const int4*)(ksrc);
      int4 v1 = *(const int4*)(ksrc + 8);
      __syncthreads();
      *(int4*)&KV[cr * 72 + cc] = v0;
      *(int4*)&KV[cr * 72 + cc + 8] = v1;
      __syncthreads();
#pragma unroll
      for (int n = 0; n < 4; n++)
#pragma unroll
        for (int kd = 0; kd < 2; kd++) {
          bfrag kf = *(const bfrag*)&KV[(n * 16 + l16) * 72 + kd * 32 + quad * 8];
          sacc[kc * 4 + n] = __builtin_amdgcn_mfma_f32_16x16x32_bf16(qf[kd], kf, sacc[kc * 4 + n], 0, 0, 0);
        }
    }
  }
  int nfr = (qt + 1) * 4;
  const float scale = 0.125f;
  float mx[4] = {-1e30f, -1e30f, -1e30f, -1e30f};
#pragma unroll
  for (int n = 0; n < 16; n++) {
    if (n < nfr) {
      int col = n * 16 + l16;
#pragma unroll
      for (int r = 0; r < 4; r++)
        if (col <= q0 + quad * 4 + r) mx[r] = fmaxf(mx[r], sacc[n][r]);
    }
  }
#pragma unroll
  for (int off = 1; off < 16; off <<= 1)
#pragma unroll
    for (int r = 0; r < 4; r++) mx[r] = fmaxf(mx[r], __shfl_xor(mx[r], off));
  float ls[4] = {0.f, 0.f, 0.f, 0.f};
#pragma unroll
  for (int n = 0; n < 16; n++) {
    if (n < nfr) {
      int col = n * 16 + l16;
#pragma unroll
      for (int r = 0; r < 4; r++) {
        float p = (col <= q0 + quad * 4 + r) ? __expf((sacc[n][r] - mx[r]) * scale) : 0.f;
        Pl[wid][quad * 4 + r][col] = f2b(p);
        ls[r] += p;
      }
    }
  }
#pragma unroll
  for (int off = 1; off < 16; off <<= 1)
#pragma unroll
    for (int r = 0; r < 4; r++) ls[r] += __shfl_xor(ls[r], off);
  float rl[4];
#pragma unroll
  for (int r = 0; r < 4; r++) rl[r] = 1.0f / ls[r];

  f32x4 oacc[4];
#pragma unroll
  for (int n = 0; n < 4; n++) oacc[n] = (f32x4){0.f, 0.f, 0.f, 0.f};
#pragma unroll
  for (int kc = 0; kc < 4; kc++) {
    if (kc <= qt) {
      const short* vsrc = vtg + (size_t)bh * 64 * 256 + cr * 256 + kc * 64 + cc;
      int4 v0 = *(const int4*)(vsrc);
      int4 v1 = *(const int4*)(vsrc + 8);
      __syncthreads();
      *(int4*)&KV[cr * 72 + cc] = v0;
      *(int4*)&KV[cr * 72 + cc + 8] = v1;
      __syncthreads();
#pragma unroll
      for (int kk = 0; kk < 2; kk++) {
        bfrag pa = *(const bfrag*)&Pl[wid][l16][kc * 64 + kk * 32 + quad * 8];
#pragma unroll
        for (int n = 0; n < 4; n++) {
          bfrag vf = *(const bfrag*)&KV[(n * 16 + l16) * 72 + kk * 32 + quad * 8];
          oacc[n] = __builtin_amdgcn_mfma_f32_16x16x32_bf16(pa, vf, oacc[n], 0, 0, 0);
        }
      }
    }
  }
#pragma unroll
  for (int n = 0; n < 4; n++)
#pragma unroll
    for (int r = 0; r < 4; r++)
      outp[(size_t)(b * Pn + q0 + quad * 4 + r) * Hdim + h * 64 + n * 16 + l16] = f2b(oacc[n][r] * rl[r]);
}

// ---------------- cross-attn MFMA v5: DMA-staged dbuf K/V, 2-phase prefetch, swizzled LDS ----------------
// nh=8, dh=128, Lq=4096, Lk=256. grid (64, 16); 4 waves; wave owns 16 q-rows.
// K chunk [64 keys][128] = 16 KB, V chunk [128 d][64 keys] = 16 KB; double-buffered.
// XOR chunk-swizzle (rule #21): linear DMA dest, pre-swizzled global source column,
// same XOR on fragment read. V0/V1 DMA issued BEFORE softmax (T14 async-STAGE).
__launch_bounds__(256)
__global__ void attn_cross5(const short* __restrict__ q, const short* __restrict__ k,
                            const short* __restrict__ vt, short* __restrict__ outp) {
  int bh = blockIdx.y; int h = bh & 7, b = bh >> 3;
  int tid = threadIdx.x;
  int wid = tid >> 6, lane = tid & 63;
  int quad = lane >> 4, l16 = lane & 15;
  int q0 = blockIdx.x * 64 + wid * 16;
  __shared__ short KV[2][8192];        // 2 x 16 KB
  __shared__ short Pl[4][16][264];     // per-wave P, padded (unchanged)

  const short* qrow = q + ((size_t)(b * Slen + q0 + l16)) * Hdim + h * 128 + quad * 8;
  bfrag qf[4];
#pragma unroll
  for (int kd = 0; kd < 4; kd++) qf[kd] = *(const bfrag*)(qrow + kd * 32);

  const short* kbase = k + (size_t)(b * Pn) * Hdim + h * 128;
  const short* vbase = vt + (size_t)bh * 32768;
  int krow = tid >> 4;                       // 0..15 (K staging row base)
  int vrow = tid >> 3;                       // 0..31 (V staging row base)
  int swzK = (tid & 15) ^ (krow & 7);        // pre-swizzled K source chunk (row&7 = krow&7)
  int swzV = (tid & 7) ^ (vrow & 7);         // pre-swizzled V source chunk
  int s3 = l16 & 7;                          // read-side swizzle key (row&7)

  f32x4 sacc[16];
#pragma unroll
  for (int n = 0; n < 16; n++) sacc[n] = (f32x4){0.f, 0.f, 0.f, 0.f};

  // ---- stage K chunk 0 ----
  {
    const short* src = kbase + (size_t)krow * Hdim + swzK * 8;
    short* dst = &KV[0][tid * 8];
#pragma unroll
    for (int r = 0; r < 4; r++)
      gload16(src + (size_t)(r * 16) * Hdim, dst + r * 2048);
  }
  asm volatile("s_waitcnt vmcnt(0)" ::: "memory");
  __builtin_amdgcn_s_barrier();

  // ---- QK^T, 2-phase ----
#pragma unroll
  for (int kc = 0; kc < 4; kc++) {
    if (kc < 3) {
      const short* src = kbase + (size_t)((kc + 1) * 64 + krow) * Hdim + swzK * 8;
      short* dst = &KV[(kc + 1) & 1][tid * 8];
#pragma unroll
      for (int r = 0; r < 4; r++)
        gload16(src + (size_t)(r * 16) * Hdim, dst + r * 2048);
    }
    const short* kv = KV[kc & 1];
#pragma unroll
    for (int n = 0; n < 4; n++) {
      int roff = (n * 16 + l16) * 128;
#pragma unroll
      for (int kd = 0; kd < 4; kd++) {
        bfrag kf = *(const bfrag*)&kv[roff + (((kd * 4 + quad) ^ s3) * 8)];
        sacc[kc * 4 + n] = __builtin_amdgcn_mfma_f32_16x16x32_bf16(qf[kd], kf, sacc[kc * 4 + n], 0, 0, 0);
      }
    }
    asm volatile("s_waitcnt vmcnt(0)" ::: "memory");
    __builtin_amdgcn_s_barrier();
  }

  // ---- issue V chunks 0,1 (latency hidden under softmax) ----
  {
    const short* src0 = vbase + (size_t)vrow * 256 + swzV * 8;
    const short* src1 = src0 + 64;
#pragma unroll
    for (int r = 0; r < 4; r++) {
      gload16(src0 + (size_t)(r * 32) * 256, &KV[0][tid * 8 + r * 2048]);
      gload16(src1 + (size_t)(r * 32) * 256, &KV[1][tid * 8 + r * 2048]);
    }
  }

  // ---- softmax (per-wave; Pl slice is wave-private) ----
  const float scale = 0.088388347648318447f;
  float mx[4] = {-1e30f, -1e30f, -1e30f, -1e30f};
#pragma unroll
  for (int n = 0; n < 16; n++)
#pragma unroll
    for (int r = 0; r < 4; r++) mx[r] = fmaxf(mx[r], sacc[n][r]);
#pragma unroll
  for (int off = 1; off < 16; off <<= 1)
#pragma unroll
    for (int r = 0; r < 4; r++) mx[r] = fmaxf(mx[r], __shfl_xor(mx[r], off));
  float ls[4] = {0.f, 0.f, 0.f, 0.f};
#pragma unroll
  for (int n = 0; n < 16; n++)
#pragma unroll
    for (int r = 0; r < 4; r++) {
      float p = __expf((sacc[n][r] - mx[r]) * scale);
      Pl[wid][quad * 4 + r][n * 16 + l16] = f2b(p);
      ls[r] += p;
    }
#pragma unroll
  for (int off = 1; off < 16; off <<= 1)
#pragma unroll
    for (int r = 0; r < 4; r++) ls[r] += __shfl_xor(ls[r], off);
  float rl[4];
#pragma unroll
  for (int r = 0; r < 4; r++) rl[r] = 1.0f / ls[r];

  asm volatile("s_waitcnt vmcnt(0)" ::: "memory");   // V0,V1 landed
  __builtin_amdgcn_s_barrier();

  // ---- PV, 2-phase over 4 V chunks ----
  f32x4 oacc[8];
#pragma unroll
  for (int n = 0; n < 8; n++) oacc[n] = (f32x4){0.f, 0.f, 0.f, 0.f};

#define PVCHUNK(KC, BUF)                                                              \
  do {                                                                                \
    const short* vv = (BUF);                                                          \
    _Pragma("unroll")                                                                 \
    for (int kk = 0; kk < 2; kk++) {                                                  \
      bfrag pa = *(const bfrag*)&Pl[wid][l16][(KC) * 64 + kk * 32 + quad * 8];        \
      _Pragma("unroll")                                                               \
      for (int n = 0; n < 8; n++) {                                                   \
        bfrag vf = *(const bfrag*)&vv[(n * 16 + l16) * 64 + (((kk * 4 + quad) ^ s3) * 8)]; \
        oacc[n] = __builtin_amdgcn_mfma_f32_16x16x32_bf16(pa, vf, oacc[n], 0, 0, 0);  \
      }                                                                               \
    }                                                                                 \
  } while (0)

#define STAGEV(KC, BUF)                                                               \
  do {                                                                                \
    const short* src = vbase + (size_t)vrow * 256 + (KC) * 64 + swzV * 8;             \
    short* dst = (BUF) + tid * 8;                                                     \
    _Pragma("unroll")                                                                 \
    for (int r = 0; r < 4; r++)                                                       \
      gload16(src + (size_t)(r * 32) * 256, dst + r * 2048);                          \
  } while (0)

  PVCHUNK(0, KV[0]);
  __builtin_amdgcn_s_barrier();                      // all waves done reading buf0
  STAGEV(2, KV[0]);
  PVCHUNK(1, KV[1]);
  __builtin_amdgcn_s_barrier();                      // all waves done reading buf1
  STAGEV(3, KV[1]);
  asm volatile("s_waitcnt vmcnt(4)" ::: "memory");   // own V2 loads retired (V3 in flight)
  __builtin_amdgcn_s_barrier();                      // => all threads' V2 landed
  PVCHUNK(2, KV[0]);
  asm volatile("s_waitcnt vmcnt(0)" ::: "memory");   // V3 landed
  __builtin_amdgcn_s_barrier();
  PVCHUNK(3, KV[1]);
#undef PVCHUNK
#undef STAGEV

#pragma unroll
  for (int n = 0; n < 8; n++)
#pragma unroll
    for (int r = 0; r < 4; r++)
      outp[(size_t)(b * Slen + q0 + quad * 4 + r) * Hdim + h * 128 + n * 16 + l16] = f2b(oacc[n][r] * rl[r]);
}

extern "C" void kernel_launch(void* const* d_in, const int* in_sizes, int n_in,
                              void* d_out, int out_size, void* d_ws, size_t ws_size,
                              hipStream_t stream) {
  const int*   byte_seq = (const int*)d_in[0];
  const int*   pbound   = (const int*)d_in[1];
  const float* emb      = (const float*)d_in[2];
  const float* g_ln1_g  = (const float*)d_in[3];
  const float* g_ln1_b  = (const float*)d_in[4];
  const float* g_wqkv   = (const float*)d_in[5];
  const float* g_bqkv   = (const float*)d_in[6];
  const float* g_wo     = (const float*)d_in[7];
  const float* g_bo     = (const float*)d_in[8];
  const float* g_ln2_g  = (const float*)d_in[9];
  const float* g_ln2_b  = (const float*)d_in[10];
  const float* g_w1     = (const float*)d_in[11];
  const float* g_b1     = (const float*)d_in[12];
  const float* g_w2     = (const float*)d_in[13];
  const float* g_b2     = (const float*)d_in[14];
  const float* fn_g     = (const float*)d_in[15];
  const float* fn_b     = (const float*)d_in[16];
  const float* ca_ln_g  = (const float*)d_in[17];
  const float* ca_ln_b  = (const float*)d_in[18];
  const float* ca_wqkv  = (const float*)d_in[19];
  const float* ca_bqkv  = (const float*)d_in[20];
  const float* ca_wo    = (const float*)d_in[21];
  const float* ca_bo    = (const float*)d_in[22];
  const float* head_w   = (const float*)d_in[23];
  const float* head_b   = (const float*)d_in[24];
  float* out = (float*)d_out;

  // ---- workspace layout ----
  float* x       = (float*)d_ws;                 // 8388608 f32
  float* patches = x + 8388608;                  // 524288
  float* vbuf    = patches + 524288;             // 524288
  float* w2part  = vbuf + 524288;                // 2097152 (4 x 512x1024 partials)
  int*   pid     = (int*)(w2part + 2097152);     // 8192 ints
  short* nbuf    = (short*)(pid + 8192);         // 524288 bf16
  short* attn_o  = nbuf + 524288;                // 524288
  short* mid     = attn_o + 524288;              // 2097152
  short* qn      = mid + 2097152;                // 8388608 (LN(x); reused as caout)
  short* qb      = qn + 8388608;                 // 8388608
  short* xb      = qb + 8388608;                 // 8388608
  short* kb      = xb + 8388608;                 // 524288 (cross K bf16)
  short* vt      = kb + 524288;                  // 524288 (cross V^T bf16)
  short* qkvb    = vt + 524288;                  // 1572864 (layer qkv bf16)
  short* vtg     = qkvb + 1572864;               // 524288 (global V^T bf16)
  short* wqkv_t  = vtg + 524288;                 // 12582912
  short* wo_t    = wqkv_t + 12582912;            // 4194304
  short* w1_t    = wo_t + 4194304;               // 16777216
  short* w2_t    = w1_t + 16777216;              // 16777216
  short* caq_t   = w2_t + 16777216;              // 1048576
  short* cak_t   = caq_t + 1048576;              // 1048576
  short* cav_t   = cak_t + 1048576;              // 1048576
  short* cawo_t  = cav_t + 1048576;              // 1048576
  short* head_t  = cawo_t + 1048576;             // 262144
  short* caout   = qn;                           // alias (qn dead after q-proj)

  // 1. byte embeddings (+fused cross-attn q LayerNorm), patch ids, pooling
  embed_ln_kernel<<<Bsz * Slen, 256, 0, stream>>>(byte_seq, emb, ca_ln_g, ca_ln_b, x, qn);
  pid_kernel<<<(Bsz * Slen) / 256, 256, 0, stream>>>(pbound, pid);
  pool_kernel<<<Bsz * Pn, 256, 0, stream>>>(x, pid, patches);

  // 2. weight convert + transpose to bf16 [N,K]
  wconv_kernel<<<dim3(96, 32, 4), 256, 0, stream>>>(g_wqkv, wqkv_t, 3072, 1024, 3145728, 3145728);
  wconv_kernel<<<dim3(32, 32, 4), 256, 0, stream>>>(g_wo, wo_t, 1024, 1024, 1048576, 1048576);
  wconv_kernel<<<dim3(128, 32, 4), 256, 0, stream>>>(g_w1, w1_t, 4096, 1024, 4194304, 4194304);
  wconv_kernel<<<dim3(32, 128, 4), 256, 0, stream>>>(g_w2, w2_t, 1024, 4096, 4194304, 4194304);
  wconv_kernel<<<dim3(32, 32, 3), 256, 0, stream>>>(ca_wqkv, caq_t, 3072, 1024, 1024, 1048576);
  wconv_kernel<<<dim3(32, 32, 1), 256, 0, stream>>>(ca_wo, cawo_t, 1024, 1024, 0, 0);
  wconv_kernel<<<dim3(8, 32, 1), 256, 0, stream>>>(head_w, head_t, 256, 1024, 0, 0);

  // 3. global transformer layers
  for (int l = 0; l < NLAY; ++l) {
    ln_kernel<1><<<Bsz * Pn, 256, 0, stream>>>(patches, g_ln1_g + l * Hdim, g_ln1_b + l * Hdim, nbuf);
    gemm_bf16_64<0, 1, 0><<<dim3(48, 8), 256, 0, stream>>>(
        nbuf, wqkv_t + (size_t)l * 3145728, g_bqkv + l * 3072, nullptr, qkvb, 3072, 1024);
    vtg_kernel<<<dim3(8, 2, 32), 256, 0, stream>>>(qkvb, vtg);
    attn_global3<<<dim3(4, 32), 256, 0, stream>>>(qkvb, vtg, attn_o);
    gemm_bf16_64<2, 0, 0><<<dim3(16, 8), 256, 0, stream>>>(
        attn_o, wo_t + (size_t)l * 1048576, g_bo + l * Hdim, patches, patches, 1024, 1024);
    ln_kernel<1><<<Bsz * Pn, 256, 0, stream>>>(patches, g_ln2_g + l * Hdim, g_ln2_b + l * Hdim, nbuf);
    gemm_bf16_64<1, 1, 0><<<dim3(64, 8), 256, 0, stream>>>(
        nbuf, w1_t + (size_t)l * 4194304, g_b1 + l * 4096, nullptr, mid, 4096, 1024);
    gemm_splitk<<<dim3(16, 8, 4), 256, 0, stream>>>(
        mid, w2_t + (size_t)l * 4194304, w2part, 4096, 1024);
    w2red_kernel<<<512, 256, 0, stream>>>(w2part, g_b2 + l * Hdim, patches);
  }

  // 4. final norm (f32, in-place), then cross-attn LN of patches -> bf16
  ln_kernel<0><<<Bsz * Pn, 256, 0, stream>>>(patches, fn_g, fn_b, patches);
  ln_kernel<1><<<Bsz * Pn, 256, 0, stream>>>(patches, ca_ln_g, ca_ln_b, nbuf);

  // 5. k (bf16 out), v (f32 out -> transposed bf16)
  gemm_bf16_64<0, 1, 0><<<dim3(16, 8), 256, 0, stream>>>(
      nbuf, cak_t, ca_bqkv + 1024, nullptr, kb, 1024, 1024);
  gemm_bf16_64<0, 0, 0><<<dim3(16, 8), 256, 0, stream>>>(
      nbuf, cav_t, ca_bqkv + 2048, nullptr, vbuf, 1024, 1024);
  vt_kernel<<<dim3(8, 4, 16), 256, 0, stream>>>(vbuf, vt);

  // 6. q projection from fused LN(x) -> bf16 (M=8192: swizzle for A-panel L2 reuse)
  gemm_bf16<0, 1, 1><<<dim3(8, 64), 256, 0, stream>>>(
      qn, caq_t, ca_bqkv, nullptr, qb, 1024, 1024);

  // 7. MFMA cross attention v5 (qn dead; caout aliases it)
  attn_cross5<<<dim3(64, 16), 256, 0, stream>>>(qb, kb, vt, caout);

  // 8. output projection + residual -> xb (bf16, feeds head)
  gemm_bf16<2, 1, 1><<<dim3(8, 64), 256, 0, stream>>>(
      caout, cawo_t, ca_bo, x, xb, 1024, 1024);

  // 9. head (M=8192: swizzle)
  gemm_bf16_64<0, 0, 1><<<dim3(4, 128), 256, 0, stream>>>(
      xb, head_t, head_b, nullptr, out, 256, 1024);
}